// Round 14
// baseline (44.169 us; speedup 1.0000x reference)
//
#include <hip/hip_runtime.h>

// Fast Tucker-Taylor forward. Round 14: K2 t2 re-tiled BM=64 for occupancy
// (1024 t2 blocks + 32 t1 = 4.1 blocks/CU, was 2.1).
//   K1 prep_gemmx : X-GEMM 1 barrier/step, LDS dbuf, depth-2 prefetch (r13).
//   K2 kron_fused : t2 BM=64,BN=64, 2 K-slices/interval, 16 barriers.
//   K3 gemm_y     : unchanged (r11).
//
// Z f16 cols: z00 0..31 | z10 32..63 | z11 64..95 | z20 96..127 | z21 128..159 | z22 160..191

typedef float f4 __attribute__((ext_vector_type(4)));
typedef _Float16 h8 __attribute__((ext_vector_type(8)));
typedef _Float16 h4 __attribute__((ext_vector_type(4)));
typedef unsigned int u32x4 __attribute__((ext_vector_type(4)));

// ws byte offsets
#define ZH_OFF  0u           // 4096*192 f16 = 1,572,864 B
#define TH_OFF  1572864u     // 4096*64 f16  =   524,288 B
#define OCH_OFF 2097152u     // 1024*96 f16  =   196,608 B
#define G2H_OFF 2293760u     // 1024*1024 f16 = 2,097,152 B (end 4,390,912)

__device__ __forceinline__ h8 splat8(unsigned int u) {
    _Float16 s = __builtin_bit_cast(_Float16, (unsigned short)(u & 0xffffu));
    return h8{ s, s, s, s, s, s, s, s };
}

// Integer-only broadcast-pair staging (r9 miscompile fix): 16 halves
// (2 x uint4) -> 16 u32 broadcast pairs.
__device__ __forceinline__ void stage_bcast16(const _Float16* zsrc, unsigned int* dst) {
    u32x4 u0 = *(const u32x4*)zsrc;
    u32x4 u1 = *(const u32x4*)(zsrc + 8);
    #pragma unroll
    for (int k = 0; k < 4; ++k) {
        dst[2*k]       = (u0[k] & 0xffffu) * 0x00010001u;
        dst[2*k + 1]   = (u0[k] >> 16)     * 0x00010001u;
        dst[8 + 2*k]   = (u1[k] & 0xffffu) * 0x00010001u;
        dst[8 + 2*k+1] = (u1[k] >> 16)     * 0x00010001u;
    }
}

// ---------------- K1: prep + X-GEMM (r13 verbatim) ----------------
__global__ __launch_bounds__(256) void prep_gemmx(
    const float* __restrict__ X,
    const float* __restrict__ I0, const float* __restrict__ I1, const float* __restrict__ I2,
    const float* __restrict__ O0, const float* __restrict__ O1, const float* __restrict__ O2,
    const float* __restrict__ G0, const float* __restrict__ G2,
    _Float16* __restrict__ Och, _Float16* __restrict__ G2h, _Float16* __restrict__ Z)
{
    const int bx = blockIdx.x;
    const int t = threadIdx.x;
    if (bx >= 192) {
        if (bx < 1216) {           // G2 -> f16
            int i = ((bx - 192) * 256 + t) * 4;
            f4 v = *(const f4*)(G2 + i);
            h4 o = { (_Float16)v[0], (_Float16)v[1], (_Float16)v[2], (_Float16)v[3] };
            *(h4*)(G2h + i) = o;
        } else {                   // Och
            int idx = (bx - 1216) * 256 + t;
            int o = idx / 96, j = idx - o * 96;
            float v;
            if (j < 32) {
                v = 0.f;
                #pragma unroll
                for (int q = 0; q < 32; ++q) v += O0[o*32 + q] * G0[q*32 + j];
            } else if (j < 64) v = O1[o*32 + (j - 32)];
            else               v = O2[o*32 + (j - 64)];
            Och[idx] = (_Float16)v;
        }
        return;
    }
    __shared__ _Float16 As[2][64 * 64];
    __shared__ _Float16 Bs[2][64 * 64];
    const int work = (bx & 7) * 24 + (bx >> 3);       // XCD-chunked (192=8*24)
    const int m0 = (work / 3) * 64, n0 = (work % 3) * 64;
    const int wid = t >> 6, lane = t & 63;
    const int wr = wid >> 1, wc = wid & 1;
    const int lr = lane & 15, lg = lane >> 4;
    const int arow = t >> 2, aq = t & 3;

    const float* xbase = X + (size_t)(m0 + arow) * 1024 + aq * 16;
    const int wrow = n0 + arow;
    const float* wbase = (wrow < 32) ? I0 + (size_t)wrow * 1024
                       : (wrow < 96) ? I1 + (size_t)(wrow - 32) * 1024
                                     : I2 + (size_t)(wrow - 96) * 1024;
    wbase += aq * 16;
    const int sw0 = arow * 64 + (((aq * 2)     ^ (arow & 7)) << 3);
    const int sw1 = arow * 64 + (((aq * 2 + 1) ^ (arow & 7)) << 3);

    f4 xa[2][4], wa[2][4];
    #define LOADX(set, step) { \
        const float* xp = xbase + (step) * 64; \
        const float* wp = wbase + (step) * 64; \
        _Pragma("unroll") \
        for (int q = 0; q < 4; ++q) { xa[set][q] = *(const f4*)(xp + q*4); wa[set][q] = *(const f4*)(wp + q*4); } }
    #define STAGE(set, buf) { \
        h8 ha0, ha1, hb0, hb1; \
        _Pragma("unroll") \
        for (int j = 0; j < 4; ++j) { \
            ha0[j] = (_Float16)xa[set][0][j]; ha0[4+j] = (_Float16)xa[set][1][j]; \
            ha1[j] = (_Float16)xa[set][2][j]; ha1[4+j] = (_Float16)xa[set][3][j]; \
            hb0[j] = (_Float16)wa[set][0][j]; hb0[4+j] = (_Float16)wa[set][1][j]; \
            hb1[j] = (_Float16)wa[set][2][j]; hb1[4+j] = (_Float16)wa[set][3][j]; \
        } \
        *(h8*)&As[buf][sw0] = ha0; *(h8*)&As[buf][sw1] = ha1; \
        *(h8*)&Bs[buf][sw0] = hb0; *(h8*)&Bs[buf][sw1] = hb1; }

    LOADX(0, 0); LOADX(1, 1);
    STAGE(0, 0);
    LOADX(0, 2);

    f4 acc[2][2];
    #pragma unroll
    for (int mt = 0; mt < 2; ++mt)
        #pragma unroll
        for (int nt = 0; nt < 2; ++nt) acc[mt][nt] = f4{0.f,0.f,0.f,0.f};

    #pragma unroll
    for (int s = 0; s < 16; ++s) {
        const int cur = s & 1;
        __syncthreads();
        if (s < 15) STAGE((s + 1) & 1, cur ^ 1);
        if (s < 13) LOADX((s + 1) & 1, s + 3);
        #pragma unroll
        for (int ks = 0; ks < 2; ++ks) {
            h8 av[2], bv[2];
            #pragma unroll
            for (int mt = 0; mt < 2; ++mt) {
                int row = wr * 32 + mt * 16 + lr, gg = ks * 4 + lg;
                av[mt] = *(const h8*)&As[cur][row * 64 + ((gg ^ (row & 7)) << 3)];
            }
            #pragma unroll
            for (int nt = 0; nt < 2; ++nt) {
                int row = wc * 32 + nt * 16 + lr, gg = ks * 4 + lg;
                bv[nt] = *(const h8*)&Bs[cur][row * 64 + ((gg ^ (row & 7)) << 3)];
            }
            #pragma unroll
            for (int mt = 0; mt < 2; ++mt)
                #pragma unroll
                for (int nt = 0; nt < 2; ++nt)
                    acc[mt][nt] = __builtin_amdgcn_mfma_f32_16x16x32_f16(av[mt], bv[nt], acc[mt][nt], 0, 0, 0);
        }
    }
    #undef LOADX
    #undef STAGE
    #pragma unroll
    for (int mt = 0; mt < 2; ++mt)
        #pragma unroll
        for (int nt = 0; nt < 2; ++nt)
            #pragma unroll
            for (int i = 0; i < 4; ++i)
                Z[(size_t)(m0 + wr*32 + mt*16 + lg*4 + i) * 192 + n0 + wc*32 + nt*16 + lr]
                    = (_Float16)acc[mt][nt][i];
}

// ---------------- K2: fused kron t2 + t1 ----------------
// t2 (bx<1024): n0=(bx&15)*64, m0=(bx>>4)*64. BM=64,BN=64; 4 waves 2x2
//   (wave tile 32x32); 2 K-slices per barrier interval (16 barriers),
//   LDS dbuf, 2-interval prefetch; fused z22 epilogue.
// t1 (bx>=1024): m0=(bx-1024)*128, BN=32 (r11 verbatim).
__global__ __launch_bounds__(256) void kron_fused(
    const _Float16* __restrict__ Z, const _Float16* __restrict__ G2h,
    const float* __restrict__ G1, _Float16* __restrict__ T)
{
    __shared__ __align__(16) unsigned char smem[37376];
    unsigned int* Zs1 = (unsigned int*)smem;               // t2: [64][33]; t1: [128][33]
    _Float16* Bs = (_Float16*)(smem + 16896);              // t2: [2][2][64][40]; t1: [2][32][40]
    const int bx = blockIdx.x;
    const int t = threadIdx.x;
    const int wid = t >> 6, lane = t & 63;
    const int lr = lane & 15, lg = lane >> 4;
    const bool is_t2 = bx < 1024;
    const int m0 = is_t2 ? (bx >> 4) * 64 : (bx - 1024) * 128;
    const int zcol = is_t2 ? 128 : 64;                     // z21 vs z11

    {   // outer z factor -> broadcast u32 pairs (integer-only)
        const int rows2 = is_t2 ? 128 : 256;               // tasks = rows*2
        if (t < rows2) {
            int row = t >> 1, c0 = (t & 1) * 16;
            stage_bcast16(Z + (size_t)(m0 + row) * 192 + zcol + c0, Zs1 + row * 33 + c0);
        }
    }

    if (is_t2) {
        const int n0 = (bx & 15) * 64;
        const int wm0 = (wid >> 1) * 32, wn0 = (wid & 1) * 32;
        h8 a0v[2];
        #pragma unroll
        for (int mt = 0; mt < 2; ++mt)
            a0v[mt] = *(const h8*)(Z + (size_t)(m0 + wm0 + mt*16 + lr) * 192 + 96 + lg * 8);

        f4 acc[2][2];
        #pragma unroll
        for (int mt = 0; mt < 2; ++mt)
            #pragma unroll
            for (int nt = 0; nt < 2; ++nt) acc[mt][nt] = f4{0.f, 0.f, 0.f, 0.f};

        const int brow = t >> 2, bg = t & 3;
        const f4* gsrc = (const f4*)(G2h + (size_t)(n0 + brow) * 1024 + bg * 8);
        // interval i covers slices 2i, 2i+1 -> gsrc[8i], gsrc[8i+4]
        f4 brA[2], brB[2];
        brA[0] = gsrc[0];  brB[0] = gsrc[4];     // interval 0
        {   // stage interval 0 -> buf 0
            *(f4*)&Bs[0 * 5120 + 0 * 2560 + brow * 40 + bg * 8] = brA[0];
            *(f4*)&Bs[0 * 5120 + 1 * 2560 + brow * 40 + bg * 8] = brB[0];
        }
        brA[1] = gsrc[8];  brB[1] = gsrc[12];    // interval 1
        brA[0] = gsrc[16]; brB[0] = gsrc[20];    // interval 2

        #pragma unroll
        for (int i = 0; i < 16; ++i) {
            const int cur = i & 1;
            __syncthreads();
            if (i < 15) {
                const int set = (i + 1) & 1;
                *(f4*)&Bs[(cur ^ 1) * 5120 + 0 * 2560 + brow * 40 + bg * 8] = brA[set];
                *(f4*)&Bs[(cur ^ 1) * 5120 + 1 * 2560 + brow * 40 + bg * 8] = brB[set];
            }
            if (i < 13) {
                const int set = (i + 1) & 1;
                brA[set] = gsrc[(i + 3) * 8];
                brB[set] = gsrc[(i + 3) * 8 + 4];
            }
            #pragma unroll
            for (int q = 0; q < 2; ++q) {
                h8 bf0 = *(const h8*)&Bs[cur * 5120 + q * 2560 + (wn0 + lr) * 40 + lg * 8];
                h8 bf1 = *(const h8*)&Bs[cur * 5120 + q * 2560 + (wn0 + 16 + lr) * 40 + lg * 8];
                #pragma unroll
                for (int mt = 0; mt < 2; ++mt) {
                    h8 z1b = splat8(Zs1[(wm0 + mt*16 + lr) * 33 + 2*i + q]);
                    h8 af = z1b * a0v[mt];
                    acc[mt][0] = __builtin_amdgcn_mfma_f32_16x16x32_f16(af, bf0, acc[mt][0], 0, 0, 0);
                    acc[mt][1] = __builtin_amdgcn_mfma_f32_16x16x32_f16(af, bf1, acc[mt][1], 0, 0, 0);
                }
            }
        }

        __syncthreads();
        float* Ms = (float*)smem;                          // [64][66]
        #pragma unroll
        for (int mt = 0; mt < 2; ++mt)
            #pragma unroll
            for (int nt = 0; nt < 2; ++nt)
                #pragma unroll
                for (int i = 0; i < 4; ++i)
                    Ms[(wm0 + mt*16 + lg*4 + i) * 66 + wn0 + nt*16 + lr] = acc[mt][nt][i];
        __syncthreads();
        if (t < 128) {
            int row = t >> 1, rl = t & 1;
            const _Float16* z2p = Z + (size_t)(m0 + row) * 192 + 160;
            const float* mrow = Ms + row * 66 + rl * 32;
            float sum = 0.f;
            #pragma unroll
            for (int r2 = 0; r2 < 32; ++r2) sum += mrow[r2] * (float)z2p[r2];
            T[(size_t)(m0 + row) * 64 + 32 + (bx & 15) * 2 + rl] = (_Float16)sum;
        }
    } else {
        // ---- t1: kron(z11,z10) @ G1^T (r11 verbatim) ----
        h8 a0v[2];
        #pragma unroll
        for (int mt = 0; mt < 2; ++mt)
            a0v[mt] = *(const h8*)(Z + (size_t)(m0 + wid*32 + mt*16 + lr) * 192 + 32 + lg * 8);

        const int brow = t >> 3, bq = (t & 7) * 4;
        const float* g1src = G1 + (size_t)brow * 1024 + bq;
        f4 bw = *(const f4*)g1src;
        {
            h4 bh = { (_Float16)bw[0], (_Float16)bw[1], (_Float16)bw[2], (_Float16)bw[3] };
            *(h4*)&Bs[brow * 40 + bq] = bh;
        }
        bw = *(const f4*)(g1src + 32);

        f4 acc[2][2];
        #pragma unroll
        for (int mt = 0; mt < 2; ++mt)
            #pragma unroll
            for (int nt = 0; nt < 2; ++nt) acc[mt][nt] = f4{0.f,0.f,0.f,0.f};
        __syncthreads();

        for (int s = 0; s < 32; ++s) {
            const int cur = s & 1;
            if (s < 31) {
                h4 bh = { (_Float16)bw[0], (_Float16)bw[1], (_Float16)bw[2], (_Float16)bw[3] };
                *(h4*)&Bs[(cur ^ 1) * 1280 + brow * 40 + bq] = bh;
            }
            if (s < 30) bw = *(const f4*)(g1src + (s + 2) * 32);
            h8 bf[2];
            #pragma unroll
            for (int nt = 0; nt < 2; ++nt)
                bf[nt] = *(const h8*)&Bs[cur * 1280 + (nt*16 + lr) * 40 + lg * 8];
            #pragma unroll
            for (int mt = 0; mt < 2; ++mt) {
                h8 z1b = splat8(Zs1[(wid*32 + mt*16 + lr) * 33 + s]);
                h8 af = z1b * a0v[mt];
                acc[mt][0] = __builtin_amdgcn_mfma_f32_16x16x32_f16(af, bf[0], acc[mt][0], 0, 0, 0);
                acc[mt][1] = __builtin_amdgcn_mfma_f32_16x16x32_f16(af, bf[1], acc[mt][1], 0, 0, 0);
            }
            __syncthreads();
        }
        #pragma unroll
        for (int mt = 0; mt < 2; ++mt)
            #pragma unroll
            for (int nt = 0; nt < 2; ++nt)
                #pragma unroll
                for (int i = 0; i < 4; ++i)
                    T[(size_t)(m0 + wid*32 + mt*16 + lg*4 + i) * 64 + nt*16 + lr]
                        = (_Float16)acc[mt][nt][i];
    }
}

// ---------------- K3: Y = const + [z00|T] @ Och^T  (BM=64, BN=128; r11) ----------------
__global__ __launch_bounds__(256) void gemm_y_mfma(
    const _Float16* __restrict__ Z, const _Float16* __restrict__ T,
    const _Float16* __restrict__ Och, const float* __restrict__ cst,
    float* __restrict__ Y)
{
    __shared__ _Float16 As[64 * 104];
    __shared__ _Float16 Bs[128 * 104];
    const int t = threadIdx.x;
    const int n0 = blockIdx.x * 128, m0 = blockIdx.y * 64;
    {   // A: 64 rows x 96 = [z00 | T]; 4 threads/row, 24 halves each
        int row = t >> 2, seg = t & 3;
        const _Float16* zp = Z + (size_t)(m0 + row) * 192;
        const _Float16* tp = T + (size_t)(m0 + row) * 64;
        _Float16* dst = As + row * 104;
        if (seg == 0) {
            *(h8*)(dst)      = *(const h8*)(zp);
            *(h8*)(dst + 8)  = *(const h8*)(zp + 8);
            *(h8*)(dst + 16) = *(const h8*)(zp + 16);
        } else if (seg == 1) {
            *(h8*)(dst + 24) = *(const h8*)(zp + 24);
            *(h8*)(dst + 32) = *(const h8*)(tp);
            *(h8*)(dst + 40) = *(const h8*)(tp + 8);
        } else if (seg == 2) {
            *(h8*)(dst + 48) = *(const h8*)(tp + 16);
            *(h8*)(dst + 56) = *(const h8*)(tp + 24);
            *(h8*)(dst + 64) = *(const h8*)(tp + 32);
        } else {
            *(h8*)(dst + 72) = *(const h8*)(tp + 40);
            *(h8*)(dst + 80) = *(const h8*)(tp + 48);
            *(h8*)(dst + 88) = *(const h8*)(tp + 56);
        }
        // B: 128 rows x 96 Och
        int row2 = t >> 1, half = t & 1;
        const _Float16* src = Och + (size_t)(n0 + row2) * 96 + half * 48;
        _Float16* bdst = Bs + row2 * 104 + half * 48;
        #pragma unroll
        for (int q = 0; q < 6; ++q) *(h8*)(bdst + q * 8) = *(const h8*)(src + q * 8);
    }
    const int wid = t >> 6, lane = t & 63;
    const int wvr = wid >> 1, wvc = wid & 1;   // 2 m-waves x 2 n-waves
    const int lr = lane & 15, lg = lane >> 4;
    float bias[4];
    #pragma unroll
    for (int nt = 0; nt < 4; ++nt) bias[nt] = cst[n0 + wvc*64 + nt*16 + lr];
    __syncthreads();

    f4 acc[2][4];
    #pragma unroll
    for (int mt = 0; mt < 2; ++mt)
        #pragma unroll
        for (int nt = 0; nt < 4; ++nt) acc[mt][nt] = f4{0.f,0.f,0.f,0.f};

    #pragma unroll
    for (int ks = 0; ks < 3; ++ks) {
        h8 av[2], bv[4];
        #pragma unroll
        for (int mt = 0; mt < 2; ++mt)
            av[mt] = *(const h8*)&As[(wvr*32 + mt*16 + lr) * 104 + ks*32 + lg*8];
        #pragma unroll
        for (int nt = 0; nt < 4; ++nt)
            bv[nt] = *(const h8*)&Bs[(wvc*64 + nt*16 + lr) * 104 + ks*32 + lg*8];
        #pragma unroll
        for (int mt = 0; mt < 2; ++mt)
            #pragma unroll
            for (int nt = 0; nt < 4; ++nt)
                acc[mt][nt] = __builtin_amdgcn_mfma_f32_16x16x32_f16(av[mt], bv[nt], acc[mt][nt], 0, 0, 0);
    }
    #pragma unroll
    for (int mt = 0; mt < 2; ++mt)
        #pragma unroll
        for (int nt = 0; nt < 4; ++nt)
            #pragma unroll
            for (int i = 0; i < 4; ++i)
                Y[(size_t)(m0 + wvr*32 + mt*16 + lg*4 + i) * 1024 + n0 + wvc*64 + nt*16 + lr]
                    = acc[mt][nt][i] + bias[nt];
}

extern "C" void kernel_launch(void* const* d_in, const int* in_sizes, int n_in,
                              void* d_out, int out_size, void* d_ws, size_t ws_size,
                              hipStream_t stream) {
    const float* X   = (const float*)d_in[0];
    const float* cst = (const float*)d_in[1];
    const float* O0  = (const float*)d_in[2];
    const float* I0  = (const float*)d_in[3];
    const float* G0  = (const float*)d_in[4];
    const float* O1  = (const float*)d_in[5];
    const float* I1  = (const float*)d_in[6];
    const float* G1  = (const float*)d_in[7];
    const float* O2  = (const float*)d_in[8];
    const float* I2  = (const float*)d_in[9];
    const float* G2  = (const float*)d_in[10];
    unsigned char* ws = (unsigned char*)d_ws;
    _Float16* Zh  = (_Float16*)(ws + ZH_OFF);
    _Float16* Th  = (_Float16*)(ws + TH_OFF);
    _Float16* Oh  = (_Float16*)(ws + OCH_OFF);
    _Float16* G2h = (_Float16*)(ws + G2H_OFF);
    float* Y = (float*)d_out;

    prep_gemmx<<<1600, 256, 0, stream>>>(X, I0, I1, I2, O0, O1, O2, G0, G2, Oh, G2h, Zh);
    kron_fused<<<1056, 256, 0, stream>>>(Zh, G2h, G1, Th);
    gemm_y_mfma<<<dim3(8, 64), 256, 0, stream>>>(Zh, Th, Oh, cst, Y);
}

// Round 15
// 43.999 us; speedup vs baseline: 1.0039x; 1.0039x over previous
//
#include <hip/hip_runtime.h>

// Fast Tucker-Taylor forward. Round 15: r13 base + K2 t2 with 4 K-slices per
// barrier interval (8 barriers/block, was 16). r14's BM=64 re-tile reverted.
//   K1 prep_gemmx : X-GEMM 1 barrier/step, LDS dbuf, depth-2 prefetch (r13).
//   K2 kron_fused : t2 BM=128,BN=64, Q=4 slices/interval, 8 barriers.
//   K3 gemm_y     : unchanged (r11).
//
// Z f16 cols: z00 0..31 | z10 32..63 | z11 64..95 | z20 96..127 | z21 128..159 | z22 160..191

typedef float f4 __attribute__((ext_vector_type(4)));
typedef _Float16 h8 __attribute__((ext_vector_type(8)));
typedef _Float16 h4 __attribute__((ext_vector_type(4)));
typedef unsigned int u32x4 __attribute__((ext_vector_type(4)));

// ws byte offsets
#define ZH_OFF  0u           // 4096*192 f16 = 1,572,864 B
#define TH_OFF  1572864u     // 4096*64 f16  =   524,288 B
#define OCH_OFF 2097152u     // 1024*96 f16  =   196,608 B
#define G2H_OFF 2293760u     // 1024*1024 f16 = 2,097,152 B (end 4,390,912)

__device__ __forceinline__ h8 splat8(unsigned int u) {
    _Float16 s = __builtin_bit_cast(_Float16, (unsigned short)(u & 0xffffu));
    return h8{ s, s, s, s, s, s, s, s };
}

// Integer-only broadcast-pair staging (r9 miscompile fix): 16 halves
// (2 x uint4) -> 16 u32 broadcast pairs.
__device__ __forceinline__ void stage_bcast16(const _Float16* zsrc, unsigned int* dst) {
    u32x4 u0 = *(const u32x4*)zsrc;
    u32x4 u1 = *(const u32x4*)(zsrc + 8);
    #pragma unroll
    for (int k = 0; k < 4; ++k) {
        dst[2*k]       = (u0[k] & 0xffffu) * 0x00010001u;
        dst[2*k + 1]   = (u0[k] >> 16)     * 0x00010001u;
        dst[8 + 2*k]   = (u1[k] & 0xffffu) * 0x00010001u;
        dst[8 + 2*k+1] = (u1[k] >> 16)     * 0x00010001u;
    }
}

// ---------------- K1: prep + X-GEMM (r13 verbatim) ----------------
__global__ __launch_bounds__(256) void prep_gemmx(
    const float* __restrict__ X,
    const float* __restrict__ I0, const float* __restrict__ I1, const float* __restrict__ I2,
    const float* __restrict__ O0, const float* __restrict__ O1, const float* __restrict__ O2,
    const float* __restrict__ G0, const float* __restrict__ G2,
    _Float16* __restrict__ Och, _Float16* __restrict__ G2h, _Float16* __restrict__ Z)
{
    const int bx = blockIdx.x;
    const int t = threadIdx.x;
    if (bx >= 192) {
        if (bx < 1216) {           // G2 -> f16
            int i = ((bx - 192) * 256 + t) * 4;
            f4 v = *(const f4*)(G2 + i);
            h4 o = { (_Float16)v[0], (_Float16)v[1], (_Float16)v[2], (_Float16)v[3] };
            *(h4*)(G2h + i) = o;
        } else {                   // Och
            int idx = (bx - 1216) * 256 + t;
            int o = idx / 96, j = idx - o * 96;
            float v;
            if (j < 32) {
                v = 0.f;
                #pragma unroll
                for (int q = 0; q < 32; ++q) v += O0[o*32 + q] * G0[q*32 + j];
            } else if (j < 64) v = O1[o*32 + (j - 32)];
            else               v = O2[o*32 + (j - 64)];
            Och[idx] = (_Float16)v;
        }
        return;
    }
    __shared__ _Float16 As[2][64 * 64];
    __shared__ _Float16 Bs[2][64 * 64];
    const int work = (bx & 7) * 24 + (bx >> 3);       // XCD-chunked (192=8*24)
    const int m0 = (work / 3) * 64, n0 = (work % 3) * 64;
    const int wid = t >> 6, lane = t & 63;
    const int wr = wid >> 1, wc = wid & 1;
    const int lr = lane & 15, lg = lane >> 4;
    const int arow = t >> 2, aq = t & 3;

    const float* xbase = X + (size_t)(m0 + arow) * 1024 + aq * 16;
    const int wrow = n0 + arow;
    const float* wbase = (wrow < 32) ? I0 + (size_t)wrow * 1024
                       : (wrow < 96) ? I1 + (size_t)(wrow - 32) * 1024
                                     : I2 + (size_t)(wrow - 96) * 1024;
    wbase += aq * 16;
    const int sw0 = arow * 64 + (((aq * 2)     ^ (arow & 7)) << 3);
    const int sw1 = arow * 64 + (((aq * 2 + 1) ^ (arow & 7)) << 3);

    f4 xa[2][4], wa[2][4];
    #define LOADX(set, step) { \
        const float* xp = xbase + (step) * 64; \
        const float* wp = wbase + (step) * 64; \
        _Pragma("unroll") \
        for (int q = 0; q < 4; ++q) { xa[set][q] = *(const f4*)(xp + q*4); wa[set][q] = *(const f4*)(wp + q*4); } }
    #define STAGE(set, buf) { \
        h8 ha0, ha1, hb0, hb1; \
        _Pragma("unroll") \
        for (int j = 0; j < 4; ++j) { \
            ha0[j] = (_Float16)xa[set][0][j]; ha0[4+j] = (_Float16)xa[set][1][j]; \
            ha1[j] = (_Float16)xa[set][2][j]; ha1[4+j] = (_Float16)xa[set][3][j]; \
            hb0[j] = (_Float16)wa[set][0][j]; hb0[4+j] = (_Float16)wa[set][1][j]; \
            hb1[j] = (_Float16)wa[set][2][j]; hb1[4+j] = (_Float16)wa[set][3][j]; \
        } \
        *(h8*)&As[buf][sw0] = ha0; *(h8*)&As[buf][sw1] = ha1; \
        *(h8*)&Bs[buf][sw0] = hb0; *(h8*)&Bs[buf][sw1] = hb1; }

    LOADX(0, 0); LOADX(1, 1);
    STAGE(0, 0);
    LOADX(0, 2);

    f4 acc[2][2];
    #pragma unroll
    for (int mt = 0; mt < 2; ++mt)
        #pragma unroll
        for (int nt = 0; nt < 2; ++nt) acc[mt][nt] = f4{0.f,0.f,0.f,0.f};

    #pragma unroll
    for (int s = 0; s < 16; ++s) {
        const int cur = s & 1;
        __syncthreads();
        if (s < 15) STAGE((s + 1) & 1, cur ^ 1);
        if (s < 13) LOADX((s + 1) & 1, s + 3);
        #pragma unroll
        for (int ks = 0; ks < 2; ++ks) {
            h8 av[2], bv[2];
            #pragma unroll
            for (int mt = 0; mt < 2; ++mt) {
                int row = wr * 32 + mt * 16 + lr, gg = ks * 4 + lg;
                av[mt] = *(const h8*)&As[cur][row * 64 + ((gg ^ (row & 7)) << 3)];
            }
            #pragma unroll
            for (int nt = 0; nt < 2; ++nt) {
                int row = wc * 32 + nt * 16 + lr, gg = ks * 4 + lg;
                bv[nt] = *(const h8*)&Bs[cur][row * 64 + ((gg ^ (row & 7)) << 3)];
            }
            #pragma unroll
            for (int mt = 0; mt < 2; ++mt)
                #pragma unroll
                for (int nt = 0; nt < 2; ++nt)
                    acc[mt][nt] = __builtin_amdgcn_mfma_f32_16x16x32_f16(av[mt], bv[nt], acc[mt][nt], 0, 0, 0);
        }
    }
    #undef LOADX
    #undef STAGE
    #pragma unroll
    for (int mt = 0; mt < 2; ++mt)
        #pragma unroll
        for (int nt = 0; nt < 2; ++nt)
            #pragma unroll
            for (int i = 0; i < 4; ++i)
                Z[(size_t)(m0 + wr*32 + mt*16 + lg*4 + i) * 192 + n0 + wc*32 + nt*16 + lr]
                    = (_Float16)acc[mt][nt][i];
}

// ---------------- K2: fused kron t2 + t1 ----------------
// t2 (bx<512): n0=(bx&15)*64, m0=(bx>>4)*128. BM=128,BN=64; Q=4 K-slices per
//   barrier interval (8 barriers), LDS dbuf, 2-interval prefetch; fused z22.
// t1 (bx>=512): m0=(bx-512)*128, BN=32 (r11 verbatim).
__global__ __launch_bounds__(256) void kron_fused(
    const _Float16* __restrict__ Z, const _Float16* __restrict__ G2h,
    const float* __restrict__ G1, _Float16* __restrict__ T)
{
    __shared__ __align__(16) unsigned char smem[57856];
    unsigned int* Zs1 = (unsigned int*)smem;               // [128][33]
    _Float16* Bs = (_Float16*)(smem + 16896);              // t2: [2][4][64][40]; t1: [2][32][40]
    const int bx = blockIdx.x;
    const int t = threadIdx.x;
    const int wid = t >> 6, lane = t & 63;
    const int lr = lane & 15, lg = lane >> 4;
    const bool is_t2 = bx < 512;
    const int m0 = is_t2 ? (bx >> 4) * 128 : (bx - 512) * 128;
    const int zcol = is_t2 ? 128 : 64;                     // z21 vs z11

    {   // outer z factor -> broadcast u32 pairs (integer-only)
        int row = t >> 1, c0 = (t & 1) * 16;
        stage_bcast16(Z + (size_t)(m0 + row) * 192 + zcol + c0, Zs1 + row * 33 + c0);
    }

    if (is_t2) {
        const int n0 = (bx & 15) * 64;
        const int wm0 = (wid >> 1) * 64, wn0 = (wid & 1) * 32;
        h8 a0v[4];
        #pragma unroll
        for (int mt = 0; mt < 4; ++mt)
            a0v[mt] = *(const h8*)(Z + (size_t)(m0 + wm0 + mt*16 + lr) * 192 + 96 + lg * 8);

        f4 acc[4][2];
        #pragma unroll
        for (int mt = 0; mt < 4; ++mt)
            #pragma unroll
            for (int nt = 0; nt < 2; ++nt) acc[mt][nt] = f4{0.f, 0.f, 0.f, 0.f};

        const int brow = t >> 2, bg = t & 3;
        const f4* gsrc = (const f4*)(G2h + (size_t)(n0 + brow) * 1024 + bg * 8);
        // slice s <-> gsrc[s*4]; interval i covers slices 4i..4i+3.
        f4 br[2][4];
        #pragma unroll
        for (int q = 0; q < 4; ++q) br[0][q] = gsrc[q * 4];          // interval 0
        #pragma unroll
        for (int q = 0; q < 4; ++q)                                  // stage -> buf 0
            *(f4*)&Bs[0 * 10240 + q * 2560 + brow * 40 + bg * 8] = br[0][q];
        #pragma unroll
        for (int q = 0; q < 4; ++q) br[1][q] = gsrc[16 + q * 4];     // interval 1
        #pragma unroll
        for (int q = 0; q < 4; ++q) br[0][q] = gsrc[32 + q * 4];     // interval 2

        #pragma unroll
        for (int i = 0; i < 8; ++i) {
            const int cur = i & 1;
            __syncthreads();
            if (i < 7) {
                const int set = (i + 1) & 1;
                #pragma unroll
                for (int q = 0; q < 4; ++q)
                    *(f4*)&Bs[(cur ^ 1) * 10240 + q * 2560 + brow * 40 + bg * 8] = br[set][q];
            }
            if (i < 5) {
                const int set = (i + 1) & 1;
                #pragma unroll
                for (int q = 0; q < 4; ++q) br[set][q] = gsrc[(i + 3) * 16 + q * 4];
            }
            #pragma unroll
            for (int q = 0; q < 4; ++q) {
                h8 bf0 = *(const h8*)&Bs[cur * 10240 + q * 2560 + (wn0 + lr) * 40 + lg * 8];
                h8 bf1 = *(const h8*)&Bs[cur * 10240 + q * 2560 + (wn0 + 16 + lr) * 40 + lg * 8];
                #pragma unroll
                for (int mt = 0; mt < 4; ++mt) {
                    h8 z1b = splat8(Zs1[(wm0 + mt*16 + lr) * 33 + 4*i + q]);
                    h8 af = z1b * a0v[mt];
                    acc[mt][0] = __builtin_amdgcn_mfma_f32_16x16x32_f16(af, bf0, acc[mt][0], 0, 0, 0);
                    acc[mt][1] = __builtin_amdgcn_mfma_f32_16x16x32_f16(af, bf1, acc[mt][1], 0, 0, 0);
                }
            }
        }

        __syncthreads();
        float* Ms = (float*)smem;                          // [128][66]
        #pragma unroll
        for (int mt = 0; mt < 4; ++mt)
            #pragma unroll
            for (int nt = 0; nt < 2; ++nt)
                #pragma unroll
                for (int i = 0; i < 4; ++i)
                    Ms[(wm0 + mt*16 + lg*4 + i) * 66 + wn0 + nt*16 + lr] = acc[mt][nt][i];
        __syncthreads();
        {
            int row = t >> 1, rl = t & 1;
            const _Float16* z2p = Z + (size_t)(m0 + row) * 192 + 160;
            const float* mrow = Ms + row * 66 + rl * 32;
            float sum = 0.f;
            #pragma unroll
            for (int r2 = 0; r2 < 32; ++r2) sum += mrow[r2] * (float)z2p[r2];
            T[(size_t)(m0 + row) * 64 + 32 + (bx & 15) * 2 + rl] = (_Float16)sum;
        }
    } else {
        // ---- t1: kron(z11,z10) @ G1^T (r11 verbatim) ----
        h8 a0v[2];
        #pragma unroll
        for (int mt = 0; mt < 2; ++mt)
            a0v[mt] = *(const h8*)(Z + (size_t)(m0 + wid*32 + mt*16 + lr) * 192 + 32 + lg * 8);

        const int brow = t >> 3, bq = (t & 7) * 4;
        const float* g1src = G1 + (size_t)brow * 1024 + bq;
        f4 bw = *(const f4*)g1src;
        {
            h4 bh = { (_Float16)bw[0], (_Float16)bw[1], (_Float16)bw[2], (_Float16)bw[3] };
            *(h4*)&Bs[brow * 40 + bq] = bh;
        }
        bw = *(const f4*)(g1src + 32);

        f4 acc[2][2];
        #pragma unroll
        for (int mt = 0; mt < 2; ++mt)
            #pragma unroll
            for (int nt = 0; nt < 2; ++nt) acc[mt][nt] = f4{0.f,0.f,0.f,0.f};
        __syncthreads();

        for (int s = 0; s < 32; ++s) {
            const int cur = s & 1;
            if (s < 31) {
                h4 bh = { (_Float16)bw[0], (_Float16)bw[1], (_Float16)bw[2], (_Float16)bw[3] };
                *(h4*)&Bs[(cur ^ 1) * 1280 + brow * 40 + bq] = bh;
            }
            if (s < 30) bw = *(const f4*)(g1src + (s + 2) * 32);
            h8 bf[2];
            #pragma unroll
            for (int nt = 0; nt < 2; ++nt)
                bf[nt] = *(const h8*)&Bs[cur * 1280 + (nt*16 + lr) * 40 + lg * 8];
            #pragma unroll
            for (int mt = 0; mt < 2; ++mt) {
                h8 z1b = splat8(Zs1[(wid*32 + mt*16 + lr) * 33 + s]);
                h8 af = z1b * a0v[mt];
                acc[mt][0] = __builtin_amdgcn_mfma_f32_16x16x32_f16(af, bf[0], acc[mt][0], 0, 0, 0);
                acc[mt][1] = __builtin_amdgcn_mfma_f32_16x16x32_f16(af, bf[1], acc[mt][1], 0, 0, 0);
            }
            __syncthreads();
        }
        #pragma unroll
        for (int mt = 0; mt < 2; ++mt)
            #pragma unroll
            for (int nt = 0; nt < 2; ++nt)
                #pragma unroll
                for (int i = 0; i < 4; ++i)
                    T[(size_t)(m0 + wid*32 + mt*16 + lg*4 + i) * 64 + nt*16 + lr]
                        = (_Float16)acc[mt][nt][i];
    }
}

// ---------------- K3: Y = const + [z00|T] @ Och^T  (BM=64, BN=128; r11) ----------------
__global__ __launch_bounds__(256) void gemm_y_mfma(
    const _Float16* __restrict__ Z, const _Float16* __restrict__ T,
    const _Float16* __restrict__ Och, const float* __restrict__ cst,
    float* __restrict__ Y)
{
    __shared__ _Float16 As[64 * 104];
    __shared__ _Float16 Bs[128 * 104];
    const int t = threadIdx.x;
    const int n0 = blockIdx.x * 128, m0 = blockIdx.y * 64;
    {   // A: 64 rows x 96 = [z00 | T]; 4 threads/row, 24 halves each
        int row = t >> 2, seg = t & 3;
        const _Float16* zp = Z + (size_t)(m0 + row) * 192;
        const _Float16* tp = T + (size_t)(m0 + row) * 64;
        _Float16* dst = As + row * 104;
        if (seg == 0) {
            *(h8*)(dst)      = *(const h8*)(zp);
            *(h8*)(dst + 8)  = *(const h8*)(zp + 8);
            *(h8*)(dst + 16) = *(const h8*)(zp + 16);
        } else if (seg == 1) {
            *(h8*)(dst + 24) = *(const h8*)(zp + 24);
            *(h8*)(dst + 32) = *(const h8*)(tp);
            *(h8*)(dst + 40) = *(const h8*)(tp + 8);
        } else if (seg == 2) {
            *(h8*)(dst + 48) = *(const h8*)(tp + 16);
            *(h8*)(dst + 56) = *(const h8*)(tp + 24);
            *(h8*)(dst + 64) = *(const h8*)(tp + 32);
        } else {
            *(h8*)(dst + 72) = *(const h8*)(tp + 40);
            *(h8*)(dst + 80) = *(const h8*)(tp + 48);
            *(h8*)(dst + 88) = *(const h8*)(tp + 56);
        }
        // B: 128 rows x 96 Och
        int row2 = t >> 1, half = t & 1;
        const _Float16* src = Och + (size_t)(n0 + row2) * 96 + half * 48;
        _Float16* bdst = Bs + row2 * 104 + half * 48;
        #pragma unroll
        for (int q = 0; q < 6; ++q) *(h8*)(bdst + q * 8) = *(const h8*)(src + q * 8);
    }
    const int wid = t >> 6, lane = t & 63;
    const int wvr = wid >> 1, wvc = wid & 1;   // 2 m-waves x 2 n-waves
    const int lr = lane & 15, lg = lane >> 4;
    float bias[4];
    #pragma unroll
    for (int nt = 0; nt < 4; ++nt) bias[nt] = cst[n0 + wvc*64 + nt*16 + lr];
    __syncthreads();

    f4 acc[2][4];
    #pragma unroll
    for (int mt = 0; mt < 2; ++mt)
        #pragma unroll
        for (int nt = 0; nt < 4; ++nt) acc[mt][nt] = f4{0.f,0.f,0.f,0.f};

    #pragma unroll
    for (int ks = 0; ks < 3; ++ks) {
        h8 av[2], bv[4];
        #pragma unroll
        for (int mt = 0; mt < 2; ++mt)
            av[mt] = *(const h8*)&As[(wvr*32 + mt*16 + lr) * 104 + ks*32 + lg*8];
        #pragma unroll
        for (int nt = 0; nt < 4; ++nt)
            bv[nt] = *(const h8*)&Bs[(wvc*64 + nt*16 + lr) * 104 + ks*32 + lg*8];
        #pragma unroll
        for (int mt = 0; mt < 2; ++mt)
            #pragma unroll
            for (int nt = 0; nt < 4; ++nt)
                acc[mt][nt] = __builtin_amdgcn_mfma_f32_16x16x32_f16(av[mt], bv[nt], acc[mt][nt], 0, 0, 0);
    }
    #pragma unroll
    for (int mt = 0; mt < 2; ++mt)
        #pragma unroll
        for (int nt = 0; nt < 4; ++nt)
            #pragma unroll
            for (int i = 0; i < 4; ++i)
                Y[(size_t)(m0 + wvr*32 + mt*16 + lg*4 + i) * 1024 + n0 + wvc*64 + nt*16 + lr]
                    = acc[mt][nt][i] + bias[nt];
}

extern "C" void kernel_launch(void* const* d_in, const int* in_sizes, int n_in,
                              void* d_out, int out_size, void* d_ws, size_t ws_size,
                              hipStream_t stream) {
    const float* X   = (const float*)d_in[0];
    const float* cst = (const float*)d_in[1];
    const float* O0  = (const float*)d_in[2];
    const float* I0  = (const float*)d_in[3];
    const float* G0  = (const float*)d_in[4];
    const float* O1  = (const float*)d_in[5];
    const float* I1  = (const float*)d_in[6];
    const float* G1  = (const float*)d_in[7];
    const float* O2  = (const float*)d_in[8];
    const float* I2  = (const float*)d_in[9];
    const float* G2  = (const float*)d_in[10];
    unsigned char* ws = (unsigned char*)d_ws;
    _Float16* Zh  = (_Float16*)(ws + ZH_OFF);
    _Float16* Th  = (_Float16*)(ws + TH_OFF);
    _Float16* Oh  = (_Float16*)(ws + OCH_OFF);
    _Float16* G2h = (_Float16*)(ws + G2H_OFF);
    float* Y = (float*)d_out;

    prep_gemmx<<<1600, 256, 0, stream>>>(X, I0, I1, I2, O0, O1, O2, G0, G2, Oh, G2h, Zh);
    kron_fused<<<544, 256, 0, stream>>>(Zh, G2h, G1, Th);
    gemm_y_mfma<<<dim3(8, 64), 256, 0, stream>>>(Zh, Th, Oh, cst, Y);
}

// Round 16
// 40.400 us; speedup vs baseline: 1.0933x; 1.0891x over previous
//
#include <hip/hip_runtime.h>

// Fast Tucker-Taylor forward. Round 16: r13 exact (39.8us config) +
// (a) t1 blocks first in K2 (tail removal), (b) G2-cvt blocks 2x wider.
//   K1 prep_gemmx : X-GEMM 1 barrier/step, LDS dbuf, depth-2 prefetch.
//   K2 kron_fused : t1 bx<32; t2 BM=128,BN=64, Q=2, 16 barriers (r13 body).
//   K3 gemm_y     : BM=64, BN=128 (r11).
//
// Z f16 cols: z00 0..31 | z10 32..63 | z11 64..95 | z20 96..127 | z21 128..159 | z22 160..191

typedef float f4 __attribute__((ext_vector_type(4)));
typedef _Float16 h8 __attribute__((ext_vector_type(8)));
typedef _Float16 h4 __attribute__((ext_vector_type(4)));
typedef unsigned int u32x4 __attribute__((ext_vector_type(4)));

// ws byte offsets
#define ZH_OFF  0u           // 4096*192 f16 = 1,572,864 B
#define TH_OFF  1572864u     // 4096*64 f16  =   524,288 B
#define OCH_OFF 2097152u     // 1024*96 f16  =   196,608 B
#define G2H_OFF 2293760u     // 1024*1024 f16 = 2,097,152 B (end 4,390,912)

__device__ __forceinline__ h8 splat8(unsigned int u) {
    _Float16 s = __builtin_bit_cast(_Float16, (unsigned short)(u & 0xffffu));
    return h8{ s, s, s, s, s, s, s, s };
}

// Integer-only broadcast-pair staging (r9 miscompile fix): 16 halves
// (2 x uint4) -> 16 u32 broadcast pairs.
__device__ __forceinline__ void stage_bcast16(const _Float16* zsrc, unsigned int* dst) {
    u32x4 u0 = *(const u32x4*)zsrc;
    u32x4 u1 = *(const u32x4*)(zsrc + 8);
    #pragma unroll
    for (int k = 0; k < 4; ++k) {
        dst[2*k]       = (u0[k] & 0xffffu) * 0x00010001u;
        dst[2*k + 1]   = (u0[k] >> 16)     * 0x00010001u;
        dst[8 + 2*k]   = (u1[k] & 0xffffu) * 0x00010001u;
        dst[8 + 2*k+1] = (u1[k] >> 16)     * 0x00010001u;
    }
}

// ---------------- K1: prep + X-GEMM ----------------
// blocks 0..191: X-GEMM; 192..703: G2->f16 (8 elems/thread); 704..1087: Och.
__global__ __launch_bounds__(256) void prep_gemmx(
    const float* __restrict__ X,
    const float* __restrict__ I0, const float* __restrict__ I1, const float* __restrict__ I2,
    const float* __restrict__ O0, const float* __restrict__ O1, const float* __restrict__ O2,
    const float* __restrict__ G0, const float* __restrict__ G2,
    _Float16* __restrict__ Och, _Float16* __restrict__ G2h, _Float16* __restrict__ Z)
{
    const int bx = blockIdx.x;
    const int t = threadIdx.x;
    if (bx >= 192) {
        if (bx < 704) {            // G2 -> f16, 8 elements per thread
            int i = ((bx - 192) * 256 + t) * 8;
            f4 v0 = *(const f4*)(G2 + i);
            f4 v1 = *(const f4*)(G2 + i + 4);
            h4 o0 = { (_Float16)v0[0], (_Float16)v0[1], (_Float16)v0[2], (_Float16)v0[3] };
            h4 o1 = { (_Float16)v1[0], (_Float16)v1[1], (_Float16)v1[2], (_Float16)v1[3] };
            *(h4*)(G2h + i) = o0;
            *(h4*)(G2h + i + 4) = o1;
        } else {                   // Och
            int idx = (bx - 704) * 256 + t;
            int o = idx / 96, j = idx - o * 96;
            float v;
            if (j < 32) {
                v = 0.f;
                #pragma unroll
                for (int q = 0; q < 32; ++q) v += O0[o*32 + q] * G0[q*32 + j];
            } else if (j < 64) v = O1[o*32 + (j - 32)];
            else               v = O2[o*32 + (j - 64)];
            Och[idx] = (_Float16)v;
        }
        return;
    }
    __shared__ _Float16 As[2][64 * 64];
    __shared__ _Float16 Bs[2][64 * 64];
    const int work = (bx & 7) * 24 + (bx >> 3);       // XCD-chunked (192=8*24)
    const int m0 = (work / 3) * 64, n0 = (work % 3) * 64;
    const int wid = t >> 6, lane = t & 63;
    const int wr = wid >> 1, wc = wid & 1;
    const int lr = lane & 15, lg = lane >> 4;
    const int arow = t >> 2, aq = t & 3;

    const float* xbase = X + (size_t)(m0 + arow) * 1024 + aq * 16;
    const int wrow = n0 + arow;
    const float* wbase = (wrow < 32) ? I0 + (size_t)wrow * 1024
                       : (wrow < 96) ? I1 + (size_t)(wrow - 32) * 1024
                                     : I2 + (size_t)(wrow - 96) * 1024;
    wbase += aq * 16;
    const int sw0 = arow * 64 + (((aq * 2)     ^ (arow & 7)) << 3);
    const int sw1 = arow * 64 + (((aq * 2 + 1) ^ (arow & 7)) << 3);

    f4 xa[2][4], wa[2][4];
    #define LOADX(set, step) { \
        const float* xp = xbase + (step) * 64; \
        const float* wp = wbase + (step) * 64; \
        _Pragma("unroll") \
        for (int q = 0; q < 4; ++q) { xa[set][q] = *(const f4*)(xp + q*4); wa[set][q] = *(const f4*)(wp + q*4); } }
    #define STAGE(set, buf) { \
        h8 ha0, ha1, hb0, hb1; \
        _Pragma("unroll") \
        for (int j = 0; j < 4; ++j) { \
            ha0[j] = (_Float16)xa[set][0][j]; ha0[4+j] = (_Float16)xa[set][1][j]; \
            ha1[j] = (_Float16)xa[set][2][j]; ha1[4+j] = (_Float16)xa[set][3][j]; \
            hb0[j] = (_Float16)wa[set][0][j]; hb0[4+j] = (_Float16)wa[set][1][j]; \
            hb1[j] = (_Float16)wa[set][2][j]; hb1[4+j] = (_Float16)wa[set][3][j]; \
        } \
        *(h8*)&As[buf][sw0] = ha0; *(h8*)&As[buf][sw1] = ha1; \
        *(h8*)&Bs[buf][sw0] = hb0; *(h8*)&Bs[buf][sw1] = hb1; }

    LOADX(0, 0); LOADX(1, 1);
    STAGE(0, 0);
    LOADX(0, 2);

    f4 acc[2][2];
    #pragma unroll
    for (int mt = 0; mt < 2; ++mt)
        #pragma unroll
        for (int nt = 0; nt < 2; ++nt) acc[mt][nt] = f4{0.f,0.f,0.f,0.f};

    #pragma unroll
    for (int s = 0; s < 16; ++s) {
        const int cur = s & 1;
        __syncthreads();
        if (s < 15) STAGE((s + 1) & 1, cur ^ 1);
        if (s < 13) LOADX((s + 1) & 1, s + 3);
        #pragma unroll
        for (int ks = 0; ks < 2; ++ks) {
            h8 av[2], bv[2];
            #pragma unroll
            for (int mt = 0; mt < 2; ++mt) {
                int row = wr * 32 + mt * 16 + lr, gg = ks * 4 + lg;
                av[mt] = *(const h8*)&As[cur][row * 64 + ((gg ^ (row & 7)) << 3)];
            }
            #pragma unroll
            for (int nt = 0; nt < 2; ++nt) {
                int row = wc * 32 + nt * 16 + lr, gg = ks * 4 + lg;
                bv[nt] = *(const h8*)&Bs[cur][row * 64 + ((gg ^ (row & 7)) << 3)];
            }
            #pragma unroll
            for (int mt = 0; mt < 2; ++mt)
                #pragma unroll
                for (int nt = 0; nt < 2; ++nt)
                    acc[mt][nt] = __builtin_amdgcn_mfma_f32_16x16x32_f16(av[mt], bv[nt], acc[mt][nt], 0, 0, 0);
        }
    }
    #undef LOADX
    #undef STAGE
    #pragma unroll
    for (int mt = 0; mt < 2; ++mt)
        #pragma unroll
        for (int nt = 0; nt < 2; ++nt)
            #pragma unroll
            for (int i = 0; i < 4; ++i)
                Z[(size_t)(m0 + wr*32 + mt*16 + lg*4 + i) * 192 + n0 + wc*32 + nt*16 + lr]
                    = (_Float16)acc[mt][nt][i];
}

// ---------------- K2: fused kron t1 + t2 (t1 FIRST for tail removal) -------
// t1 (bx<32): m0=bx*128, BN=32 (r11 body).
// t2 (bx>=32): bxx=bx-32; n0=(bxx&15)*64, m0=(bxx>>4)*128. BM=128,BN=64;
//   2 K-slices per barrier interval (16 barriers), LDS dbuf, 2-interval
//   prefetch; fused z22 epilogue. (r13 body)
__global__ __launch_bounds__(256) void kron_fused(
    const _Float16* __restrict__ Z, const _Float16* __restrict__ G2h,
    const float* __restrict__ G1, _Float16* __restrict__ T)
{
    __shared__ __align__(16) unsigned char smem[37376];
    unsigned int* Zs1 = (unsigned int*)smem;               // [128][33]
    _Float16* Bs = (_Float16*)(smem + 16896);              // t2: [2][2][64][40]; t1: [2][32][40]
    const int bx = blockIdx.x;
    const int t = threadIdx.x;
    const int wid = t >> 6, lane = t & 63;
    const int lr = lane & 15, lg = lane >> 4;
    const bool is_t2 = bx >= 32;
    const int bxx = bx - 32;
    const int m0 = is_t2 ? (bxx >> 4) * 128 : bx * 128;
    const int zcol = is_t2 ? 128 : 64;                     // z21 vs z11

    {   // outer z factor -> broadcast u32 pairs (integer-only)
        int row = t >> 1, c0 = (t & 1) * 16;
        stage_bcast16(Z + (size_t)(m0 + row) * 192 + zcol + c0, Zs1 + row * 33 + c0);
    }

    if (is_t2) {
        const int n0 = (bxx & 15) * 64;
        const int wm0 = (wid >> 1) * 64, wn0 = (wid & 1) * 32;
        h8 a0v[4];
        #pragma unroll
        for (int mt = 0; mt < 4; ++mt)
            a0v[mt] = *(const h8*)(Z + (size_t)(m0 + wm0 + mt*16 + lr) * 192 + 96 + lg * 8);

        f4 acc[4][2];
        #pragma unroll
        for (int mt = 0; mt < 4; ++mt)
            #pragma unroll
            for (int nt = 0; nt < 2; ++nt) acc[mt][nt] = f4{0.f, 0.f, 0.f, 0.f};

        const int brow = t >> 2, bg = t & 3;
        const f4* gsrc = (const f4*)(G2h + (size_t)(n0 + brow) * 1024 + bg * 8);
        // interval i covers slices 2i, 2i+1 -> gsrc[8i], gsrc[8i+4]
        f4 brA[2], brB[2];
        brA[0] = gsrc[0];  brB[0] = gsrc[4];     // interval 0
        {   // stage interval 0 -> buf 0
            *(f4*)&Bs[0 * 5120 + 0 * 2560 + brow * 40 + bg * 8] = brA[0];
            *(f4*)&Bs[0 * 5120 + 1 * 2560 + brow * 40 + bg * 8] = brB[0];
        }
        brA[1] = gsrc[8];  brB[1] = gsrc[12];    // interval 1
        brA[0] = gsrc[16]; brB[0] = gsrc[20];    // interval 2

        #pragma unroll
        for (int i = 0; i < 16; ++i) {
            const int cur = i & 1;
            __syncthreads();
            if (i < 15) {
                const int set = (i + 1) & 1;
                *(f4*)&Bs[(cur ^ 1) * 5120 + 0 * 2560 + brow * 40 + bg * 8] = brA[set];
                *(f4*)&Bs[(cur ^ 1) * 5120 + 1 * 2560 + brow * 40 + bg * 8] = brB[set];
            }
            if (i < 13) {
                const int set = (i + 1) & 1;
                brA[set] = gsrc[(i + 3) * 8];
                brB[set] = gsrc[(i + 3) * 8 + 4];
            }
            #pragma unroll
            for (int q = 0; q < 2; ++q) {
                h8 bf0 = *(const h8*)&Bs[cur * 5120 + q * 2560 + (wn0 + lr) * 40 + lg * 8];
                h8 bf1 = *(const h8*)&Bs[cur * 5120 + q * 2560 + (wn0 + 16 + lr) * 40 + lg * 8];
                #pragma unroll
                for (int mt = 0; mt < 4; ++mt) {
                    h8 z1b = splat8(Zs1[(wm0 + mt*16 + lr) * 33 + 2*i + q]);
                    h8 af = z1b * a0v[mt];
                    acc[mt][0] = __builtin_amdgcn_mfma_f32_16x16x32_f16(af, bf0, acc[mt][0], 0, 0, 0);
                    acc[mt][1] = __builtin_amdgcn_mfma_f32_16x16x32_f16(af, bf1, acc[mt][1], 0, 0, 0);
                }
            }
        }

        __syncthreads();
        float* Ms = (float*)smem;                          // [128][66]
        #pragma unroll
        for (int mt = 0; mt < 4; ++mt)
            #pragma unroll
            for (int nt = 0; nt < 2; ++nt)
                #pragma unroll
                for (int i = 0; i < 4; ++i)
                    Ms[(wm0 + mt*16 + lg*4 + i) * 66 + wn0 + nt*16 + lr] = acc[mt][nt][i];
        __syncthreads();
        {
            int row = t >> 1, rl = t & 1;
            const _Float16* z2p = Z + (size_t)(m0 + row) * 192 + 160;
            const float* mrow = Ms + row * 66 + rl * 32;
            float sum = 0.f;
            #pragma unroll
            for (int r2 = 0; r2 < 32; ++r2) sum += mrow[r2] * (float)z2p[r2];
            T[(size_t)(m0 + row) * 64 + 32 + (bxx & 15) * 2 + rl] = (_Float16)sum;
        }
    } else {
        // ---- t1: kron(z11,z10) @ G1^T (r11 verbatim) ----
        h8 a0v[2];
        #pragma unroll
        for (int mt = 0; mt < 2; ++mt)
            a0v[mt] = *(const h8*)(Z + (size_t)(m0 + wid*32 + mt*16 + lr) * 192 + 32 + lg * 8);

        const int brow = t >> 3, bq = (t & 7) * 4;
        const float* g1src = G1 + (size_t)brow * 1024 + bq;
        f4 bw = *(const f4*)g1src;
        {
            h4 bh = { (_Float16)bw[0], (_Float16)bw[1], (_Float16)bw[2], (_Float16)bw[3] };
            *(h4*)&Bs[brow * 40 + bq] = bh;
        }
        bw = *(const f4*)(g1src + 32);

        f4 acc[2][2];
        #pragma unroll
        for (int mt = 0; mt < 2; ++mt)
            #pragma unroll
            for (int nt = 0; nt < 2; ++nt) acc[mt][nt] = f4{0.f,0.f,0.f,0.f};
        __syncthreads();

        for (int s = 0; s < 32; ++s) {
            const int cur = s & 1;
            if (s < 31) {
                h4 bh = { (_Float16)bw[0], (_Float16)bw[1], (_Float16)bw[2], (_Float16)bw[3] };
                *(h4*)&Bs[(cur ^ 1) * 1280 + brow * 40 + bq] = bh;
            }
            if (s < 30) bw = *(const f4*)(g1src + (s + 2) * 32);
            h8 bf[2];
            #pragma unroll
            for (int nt = 0; nt < 2; ++nt)
                bf[nt] = *(const h8*)&Bs[cur * 1280 + (nt*16 + lr) * 40 + lg * 8];
            #pragma unroll
            for (int mt = 0; mt < 2; ++mt) {
                h8 z1b = splat8(Zs1[(wid*32 + mt*16 + lr) * 33 + s]);
                h8 af = z1b * a0v[mt];
                acc[mt][0] = __builtin_amdgcn_mfma_f32_16x16x32_f16(af, bf[0], acc[mt][0], 0, 0, 0);
                acc[mt][1] = __builtin_amdgcn_mfma_f32_16x16x32_f16(af, bf[1], acc[mt][1], 0, 0, 0);
            }
            __syncthreads();
        }
        #pragma unroll
        for (int mt = 0; mt < 2; ++mt)
            #pragma unroll
            for (int nt = 0; nt < 2; ++nt)
                #pragma unroll
                for (int i = 0; i < 4; ++i)
                    T[(size_t)(m0 + wid*32 + mt*16 + lg*4 + i) * 64 + nt*16 + lr]
                        = (_Float16)acc[mt][nt][i];
    }
}

// ---------------- K3: Y = const + [z00|T] @ Och^T  (BM=64, BN=128; r11) ----------------
__global__ __launch_bounds__(256) void gemm_y_mfma(
    const _Float16* __restrict__ Z, const _Float16* __restrict__ T,
    const _Float16* __restrict__ Och, const float* __restrict__ cst,
    float* __restrict__ Y)
{
    __shared__ _Float16 As[64 * 104];
    __shared__ _Float16 Bs[128 * 104];
    const int t = threadIdx.x;
    const int n0 = blockIdx.x * 128, m0 = blockIdx.y * 64;
    {   // A: 64 rows x 96 = [z00 | T]; 4 threads/row, 24 halves each
        int row = t >> 2, seg = t & 3;
        const _Float16* zp = Z + (size_t)(m0 + row) * 192;
        const _Float16* tp = T + (size_t)(m0 + row) * 64;
        _Float16* dst = As + row * 104;
        if (seg == 0) {
            *(h8*)(dst)      = *(const h8*)(zp);
            *(h8*)(dst + 8)  = *(const h8*)(zp + 8);
            *(h8*)(dst + 16) = *(const h8*)(zp + 16);
        } else if (seg == 1) {
            *(h8*)(dst + 24) = *(const h8*)(zp + 24);
            *(h8*)(dst + 32) = *(const h8*)(tp);
            *(h8*)(dst + 40) = *(const h8*)(tp + 8);
        } else if (seg == 2) {
            *(h8*)(dst + 48) = *(const h8*)(tp + 16);
            *(h8*)(dst + 56) = *(const h8*)(tp + 24);
            *(h8*)(dst + 64) = *(const h8*)(tp + 32);
        } else {
            *(h8*)(dst + 72) = *(const h8*)(tp + 40);
            *(h8*)(dst + 80) = *(const h8*)(tp + 48);
            *(h8*)(dst + 88) = *(const h8*)(tp + 56);
        }
        // B: 128 rows x 96 Och
        int row2 = t >> 1, half = t & 1;
        const _Float16* src = Och + (size_t)(n0 + row2) * 96 + half * 48;
        _Float16* bdst = Bs + row2 * 104 + half * 48;
        #pragma unroll
        for (int q = 0; q < 6; ++q) *(h8*)(bdst + q * 8) = *(const h8*)(src + q * 8);
    }
    const int wid = t >> 6, lane = t & 63;
    const int wvr = wid >> 1, wvc = wid & 1;   // 2 m-waves x 2 n-waves
    const int lr = lane & 15, lg = lane >> 4;
    float bias[4];
    #pragma unroll
    for (int nt = 0; nt < 4; ++nt) bias[nt] = cst[n0 + wvc*64 + nt*16 + lr];
    __syncthreads();

    f4 acc[2][4];
    #pragma unroll
    for (int mt = 0; mt < 2; ++mt)
        #pragma unroll
        for (int nt = 0; nt < 4; ++nt) acc[mt][nt] = f4{0.f,0.f,0.f,0.f};

    #pragma unroll
    for (int ks = 0; ks < 3; ++ks) {
        h8 av[2], bv[4];
        #pragma unroll
        for (int mt = 0; mt < 2; ++mt)
            av[mt] = *(const h8*)&As[(wvr*32 + mt*16 + lr) * 104 + ks*32 + lg*8];
        #pragma unroll
        for (int nt = 0; nt < 4; ++nt)
            bv[nt] = *(const h8*)&Bs[(wvc*64 + nt*16 + lr) * 104 + ks*32 + lg*8];
        #pragma unroll
        for (int mt = 0; mt < 2; ++mt)
            #pragma unroll
            for (int nt = 0; nt < 4; ++nt)
                acc[mt][nt] = __builtin_amdgcn_mfma_f32_16x16x32_f16(av[mt], bv[nt], acc[mt][nt], 0, 0, 0);
    }
    #pragma unroll
    for (int mt = 0; mt < 2; ++mt)
        #pragma unroll
        for (int nt = 0; nt < 4; ++nt)
            #pragma unroll
            for (int i = 0; i < 4; ++i)
                Y[(size_t)(m0 + wvr*32 + mt*16 + lg*4 + i) * 1024 + n0 + wvc*64 + nt*16 + lr]
                    = acc[mt][nt][i] + bias[nt];
}

extern "C" void kernel_launch(void* const* d_in, const int* in_sizes, int n_in,
                              void* d_out, int out_size, void* d_ws, size_t ws_size,
                              hipStream_t stream) {
    const float* X   = (const float*)d_in[0];
    const float* cst = (const float*)d_in[1];
    const float* O0  = (const float*)d_in[2];
    const float* I0  = (const float*)d_in[3];
    const float* G0  = (const float*)d_in[4];
    const float* O1  = (const float*)d_in[5];
    const float* I1  = (const float*)d_in[6];
    const float* G1  = (const float*)d_in[7];
    const float* O2  = (const float*)d_in[8];
    const float* I2  = (const float*)d_in[9];
    const float* G2  = (const float*)d_in[10];
    unsigned char* ws = (unsigned char*)d_ws;
    _Float16* Zh  = (_Float16*)(ws + ZH_OFF);
    _Float16* Th  = (_Float16*)(ws + TH_OFF);
    _Float16* Oh  = (_Float16*)(ws + OCH_OFF);
    _Float16* G2h = (_Float16*)(ws + G2H_OFF);
    float* Y = (float*)d_out;

    prep_gemmx<<<1088, 256, 0, stream>>>(X, I0, I1, I2, O0, O1, O2, G0, G2, Oh, G2h, Zh);
    kron_fused<<<544, 256, 0, stream>>>(Zh, G2h, G1, Th);
    gemm_y_mfma<<<dim3(8, 64), 256, 0, stream>>>(Zh, Th, Oh, cst, Y);
}

// Round 17
// 39.300 us; speedup vs baseline: 1.1239x; 1.0280x over previous
//
#include <hip/hip_runtime.h>

// Fast Tucker-Taylor forward. Round 17: exact r13 (best: 39.8us) + K2-t2
// Zs1 register prefetch (next interval's 8 u32 loaded an interval early).
//   K1 prep_gemmx : X-GEMM 1 barrier/step, LDS dbuf, depth-2 prefetch.
//   K2 kron_fused : t2 BM=128,BN=64, Q=2, 16 barriers, zu-prefetch.
//   K3 gemm_y     : BM=64, BN=128.
//
// Z f16 cols: z00 0..31 | z10 32..63 | z11 64..95 | z20 96..127 | z21 128..159 | z22 160..191

typedef float f4 __attribute__((ext_vector_type(4)));
typedef _Float16 h8 __attribute__((ext_vector_type(8)));
typedef _Float16 h4 __attribute__((ext_vector_type(4)));
typedef unsigned int u32x4 __attribute__((ext_vector_type(4)));

// ws byte offsets
#define ZH_OFF  0u           // 4096*192 f16 = 1,572,864 B
#define TH_OFF  1572864u     // 4096*64 f16  =   524,288 B
#define OCH_OFF 2097152u     // 1024*96 f16  =   196,608 B
#define G2H_OFF 2293760u     // 1024*1024 f16 = 2,097,152 B (end 4,390,912)

__device__ __forceinline__ h8 splat8(unsigned int u) {
    _Float16 s = __builtin_bit_cast(_Float16, (unsigned short)(u & 0xffffu));
    return h8{ s, s, s, s, s, s, s, s };
}

// Integer-only broadcast-pair staging (r9 miscompile fix): 16 halves
// (2 x uint4) -> 16 u32 broadcast pairs.
__device__ __forceinline__ void stage_bcast16(const _Float16* zsrc, unsigned int* dst) {
    u32x4 u0 = *(const u32x4*)zsrc;
    u32x4 u1 = *(const u32x4*)(zsrc + 8);
    #pragma unroll
    for (int k = 0; k < 4; ++k) {
        dst[2*k]       = (u0[k] & 0xffffu) * 0x00010001u;
        dst[2*k + 1]   = (u0[k] >> 16)     * 0x00010001u;
        dst[8 + 2*k]   = (u1[k] & 0xffffu) * 0x00010001u;
        dst[8 + 2*k+1] = (u1[k] >> 16)     * 0x00010001u;
    }
}

// ---------------- K1: prep + X-GEMM (r13 verbatim) ----------------
__global__ __launch_bounds__(256) void prep_gemmx(
    const float* __restrict__ X,
    const float* __restrict__ I0, const float* __restrict__ I1, const float* __restrict__ I2,
    const float* __restrict__ O0, const float* __restrict__ O1, const float* __restrict__ O2,
    const float* __restrict__ G0, const float* __restrict__ G2,
    _Float16* __restrict__ Och, _Float16* __restrict__ G2h, _Float16* __restrict__ Z)
{
    const int bx = blockIdx.x;
    const int t = threadIdx.x;
    if (bx >= 192) {
        if (bx < 1216) {           // G2 -> f16
            int i = ((bx - 192) * 256 + t) * 4;
            f4 v = *(const f4*)(G2 + i);
            h4 o = { (_Float16)v[0], (_Float16)v[1], (_Float16)v[2], (_Float16)v[3] };
            *(h4*)(G2h + i) = o;
        } else {                   // Och
            int idx = (bx - 1216) * 256 + t;
            int o = idx / 96, j = idx - o * 96;
            float v;
            if (j < 32) {
                v = 0.f;
                #pragma unroll
                for (int q = 0; q < 32; ++q) v += O0[o*32 + q] * G0[q*32 + j];
            } else if (j < 64) v = O1[o*32 + (j - 32)];
            else               v = O2[o*32 + (j - 64)];
            Och[idx] = (_Float16)v;
        }
        return;
    }
    __shared__ _Float16 As[2][64 * 64];
    __shared__ _Float16 Bs[2][64 * 64];
    const int work = (bx & 7) * 24 + (bx >> 3);       // XCD-chunked (192=8*24)
    const int m0 = (work / 3) * 64, n0 = (work % 3) * 64;
    const int wid = t >> 6, lane = t & 63;
    const int wr = wid >> 1, wc = wid & 1;
    const int lr = lane & 15, lg = lane >> 4;
    const int arow = t >> 2, aq = t & 3;

    const float* xbase = X + (size_t)(m0 + arow) * 1024 + aq * 16;
    const int wrow = n0 + arow;
    const float* wbase = (wrow < 32) ? I0 + (size_t)wrow * 1024
                       : (wrow < 96) ? I1 + (size_t)(wrow - 32) * 1024
                                     : I2 + (size_t)(wrow - 96) * 1024;
    wbase += aq * 16;
    const int sw0 = arow * 64 + (((aq * 2)     ^ (arow & 7)) << 3);
    const int sw1 = arow * 64 + (((aq * 2 + 1) ^ (arow & 7)) << 3);

    f4 xa[2][4], wa[2][4];
    #define LOADX(set, step) { \
        const float* xp = xbase + (step) * 64; \
        const float* wp = wbase + (step) * 64; \
        _Pragma("unroll") \
        for (int q = 0; q < 4; ++q) { xa[set][q] = *(const f4*)(xp + q*4); wa[set][q] = *(const f4*)(wp + q*4); } }
    #define STAGE(set, buf) { \
        h8 ha0, ha1, hb0, hb1; \
        _Pragma("unroll") \
        for (int j = 0; j < 4; ++j) { \
            ha0[j] = (_Float16)xa[set][0][j]; ha0[4+j] = (_Float16)xa[set][1][j]; \
            ha1[j] = (_Float16)xa[set][2][j]; ha1[4+j] = (_Float16)xa[set][3][j]; \
            hb0[j] = (_Float16)wa[set][0][j]; hb0[4+j] = (_Float16)wa[set][1][j]; \
            hb1[j] = (_Float16)wa[set][2][j]; hb1[4+j] = (_Float16)wa[set][3][j]; \
        } \
        *(h8*)&As[buf][sw0] = ha0; *(h8*)&As[buf][sw1] = ha1; \
        *(h8*)&Bs[buf][sw0] = hb0; *(h8*)&Bs[buf][sw1] = hb1; }

    LOADX(0, 0); LOADX(1, 1);
    STAGE(0, 0);
    LOADX(0, 2);

    f4 acc[2][2];
    #pragma unroll
    for (int mt = 0; mt < 2; ++mt)
        #pragma unroll
        for (int nt = 0; nt < 2; ++nt) acc[mt][nt] = f4{0.f,0.f,0.f,0.f};

    #pragma unroll
    for (int s = 0; s < 16; ++s) {
        const int cur = s & 1;
        __syncthreads();
        if (s < 15) STAGE((s + 1) & 1, cur ^ 1);
        if (s < 13) LOADX((s + 1) & 1, s + 3);
        #pragma unroll
        for (int ks = 0; ks < 2; ++ks) {
            h8 av[2], bv[2];
            #pragma unroll
            for (int mt = 0; mt < 2; ++mt) {
                int row = wr * 32 + mt * 16 + lr, gg = ks * 4 + lg;
                av[mt] = *(const h8*)&As[cur][row * 64 + ((gg ^ (row & 7)) << 3)];
            }
            #pragma unroll
            for (int nt = 0; nt < 2; ++nt) {
                int row = wc * 32 + nt * 16 + lr, gg = ks * 4 + lg;
                bv[nt] = *(const h8*)&Bs[cur][row * 64 + ((gg ^ (row & 7)) << 3)];
            }
            #pragma unroll
            for (int mt = 0; mt < 2; ++mt)
                #pragma unroll
                for (int nt = 0; nt < 2; ++nt)
                    acc[mt][nt] = __builtin_amdgcn_mfma_f32_16x16x32_f16(av[mt], bv[nt], acc[mt][nt], 0, 0, 0);
        }
    }
    #undef LOADX
    #undef STAGE
    #pragma unroll
    for (int mt = 0; mt < 2; ++mt)
        #pragma unroll
        for (int nt = 0; nt < 2; ++nt)
            #pragma unroll
            for (int i = 0; i < 4; ++i)
                Z[(size_t)(m0 + wr*32 + mt*16 + lg*4 + i) * 192 + n0 + wc*32 + nt*16 + lr]
                    = (_Float16)acc[mt][nt][i];
}

// ---------------- K2: fused kron t2 + t1 ----------------
// t2 (bx<512): n0=(bx&15)*64, m0=(bx>>4)*128. BM=128,BN=64; 2 K-slices per
//   barrier interval (16 barriers), LDS dbuf, 2-interval B prefetch,
//   zu (Zs1) register prefetch; fused z22 epilogue.
// t1 (bx>=512): m0=(bx-512)*128, BN=32 (r11 verbatim).
__global__ __launch_bounds__(256) void kron_fused(
    const _Float16* __restrict__ Z, const _Float16* __restrict__ G2h,
    const float* __restrict__ G1, _Float16* __restrict__ T)
{
    __shared__ __align__(16) unsigned char smem[37376];
    unsigned int* Zs1 = (unsigned int*)smem;               // [128][33]
    _Float16* Bs = (_Float16*)(smem + 16896);              // t2: [2][2][64][40]; t1: [2][32][40]
    const int bx = blockIdx.x;
    const int t = threadIdx.x;
    const int wid = t >> 6, lane = t & 63;
    const int lr = lane & 15, lg = lane >> 4;
    const bool is_t2 = bx < 512;
    const int m0 = is_t2 ? (bx >> 4) * 128 : (bx - 512) * 128;
    const int zcol = is_t2 ? 128 : 64;                     // z21 vs z11

    {   // outer z factor -> broadcast u32 pairs (integer-only)
        int row = t >> 1, c0 = (t & 1) * 16;
        stage_bcast16(Z + (size_t)(m0 + row) * 192 + zcol + c0, Zs1 + row * 33 + c0);
    }

    if (is_t2) {
        const int n0 = (bx & 15) * 64;
        const int wm0 = (wid >> 1) * 64, wn0 = (wid & 1) * 32;
        h8 a0v[4];
        #pragma unroll
        for (int mt = 0; mt < 4; ++mt)
            a0v[mt] = *(const h8*)(Z + (size_t)(m0 + wm0 + mt*16 + lr) * 192 + 96 + lg * 8);

        f4 acc[4][2];
        #pragma unroll
        for (int mt = 0; mt < 4; ++mt)
            #pragma unroll
            for (int nt = 0; nt < 2; ++nt) acc[mt][nt] = f4{0.f, 0.f, 0.f, 0.f};

        const int brow = t >> 2, bg = t & 3;
        const f4* gsrc = (const f4*)(G2h + (size_t)(n0 + brow) * 1024 + bg * 8);
        // interval i covers slices 2i, 2i+1 -> gsrc[8i], gsrc[8i+4]
        f4 brA[2], brB[2];
        brA[0] = gsrc[0];  brB[0] = gsrc[4];     // interval 0
        {   // stage interval 0 -> buf 0
            *(f4*)&Bs[0 * 5120 + 0 * 2560 + brow * 40 + bg * 8] = brA[0];
            *(f4*)&Bs[0 * 5120 + 1 * 2560 + brow * 40 + bg * 8] = brB[0];
        }
        brA[1] = gsrc[8];  brB[1] = gsrc[12];    // interval 1
        brA[0] = gsrc[16]; brB[0] = gsrc[20];    // interval 2

        unsigned int zu[2][2][4];                // [set][q][mt] Zs1 prefetch
        #pragma unroll
        for (int i = 0; i < 16; ++i) {
            const int cur = i & 1;
            __syncthreads();
            if (i == 0) {                        // first reads after barrier (Zs1 ready)
                #pragma unroll
                for (int q = 0; q < 2; ++q)
                    #pragma unroll
                    for (int mt = 0; mt < 4; ++mt)
                        zu[0][q][mt] = Zs1[(wm0 + mt*16 + lr) * 33 + q];
            }
            if (i < 15) {
                const int set = (i + 1) & 1;
                *(f4*)&Bs[(cur ^ 1) * 5120 + 0 * 2560 + brow * 40 + bg * 8] = brA[set];
                *(f4*)&Bs[(cur ^ 1) * 5120 + 1 * 2560 + brow * 40 + bg * 8] = brB[set];
                #pragma unroll
                for (int q = 0; q < 2; ++q)      // prefetch next interval's z1 pairs
                    #pragma unroll
                    for (int mt = 0; mt < 4; ++mt)
                        zu[set][q][mt] = Zs1[(wm0 + mt*16 + lr) * 33 + 2*(i+1) + q];
            }
            if (i < 13) {
                const int set = (i + 1) & 1;
                brA[set] = gsrc[(i + 3) * 8];
                brB[set] = gsrc[(i + 3) * 8 + 4];
            }
            #pragma unroll
            for (int q = 0; q < 2; ++q) {
                h8 bf0 = *(const h8*)&Bs[cur * 5120 + q * 2560 + (wn0 + lr) * 40 + lg * 8];
                h8 bf1 = *(const h8*)&Bs[cur * 5120 + q * 2560 + (wn0 + 16 + lr) * 40 + lg * 8];
                #pragma unroll
                for (int mt = 0; mt < 4; ++mt) {
                    h8 z1b = splat8(zu[cur][q][mt]);
                    h8 af = z1b * a0v[mt];
                    acc[mt][0] = __builtin_amdgcn_mfma_f32_16x16x32_f16(af, bf0, acc[mt][0], 0, 0, 0);
                    acc[mt][1] = __builtin_amdgcn_mfma_f32_16x16x32_f16(af, bf1, acc[mt][1], 0, 0, 0);
                }
            }
        }

        __syncthreads();
        float* Ms = (float*)smem;                          // [128][66]
        #pragma unroll
        for (int mt = 0; mt < 4; ++mt)
            #pragma unroll
            for (int nt = 0; nt < 2; ++nt)
                #pragma unroll
                for (int i = 0; i < 4; ++i)
                    Ms[(wm0 + mt*16 + lg*4 + i) * 66 + wn0 + nt*16 + lr] = acc[mt][nt][i];
        __syncthreads();
        {
            int row = t >> 1, rl = t & 1;
            const _Float16* z2p = Z + (size_t)(m0 + row) * 192 + 160;
            const float* mrow = Ms + row * 66 + rl * 32;
            float sum = 0.f;
            #pragma unroll
            for (int r2 = 0; r2 < 32; ++r2) sum += mrow[r2] * (float)z2p[r2];
            T[(size_t)(m0 + row) * 64 + 32 + (bx & 15) * 2 + rl] = (_Float16)sum;
        }
    } else {
        // ---- t1: kron(z11,z10) @ G1^T (r11 verbatim) ----
        h8 a0v[2];
        #pragma unroll
        for (int mt = 0; mt < 2; ++mt)
            a0v[mt] = *(const h8*)(Z + (size_t)(m0 + wid*32 + mt*16 + lr) * 192 + 32 + lg * 8);

        const int brow = t >> 3, bq = (t & 7) * 4;
        const float* g1src = G1 + (size_t)brow * 1024 + bq;
        f4 bw = *(const f4*)g1src;
        {
            h4 bh = { (_Float16)bw[0], (_Float16)bw[1], (_Float16)bw[2], (_Float16)bw[3] };
            *(h4*)&Bs[brow * 40 + bq] = bh;
        }
        bw = *(const f4*)(g1src + 32);

        f4 acc[2][2];
        #pragma unroll
        for (int mt = 0; mt < 2; ++mt)
            #pragma unroll
            for (int nt = 0; nt < 2; ++nt) acc[mt][nt] = f4{0.f,0.f,0.f,0.f};
        __syncthreads();

        for (int s = 0; s < 32; ++s) {
            const int cur = s & 1;
            if (s < 31) {
                h4 bh = { (_Float16)bw[0], (_Float16)bw[1], (_Float16)bw[2], (_Float16)bw[3] };
                *(h4*)&Bs[(cur ^ 1) * 1280 + brow * 40 + bq] = bh;
            }
            if (s < 30) bw = *(const f4*)(g1src + (s + 2) * 32);
            h8 bf[2];
            #pragma unroll
            for (int nt = 0; nt < 2; ++nt)
                bf[nt] = *(const h8*)&Bs[cur * 1280 + (nt*16 + lr) * 40 + lg * 8];
            #pragma unroll
            for (int mt = 0; mt < 2; ++mt) {
                h8 z1b = splat8(Zs1[(wid*32 + mt*16 + lr) * 33 + s]);
                h8 af = z1b * a0v[mt];
                acc[mt][0] = __builtin_amdgcn_mfma_f32_16x16x32_f16(af, bf[0], acc[mt][0], 0, 0, 0);
                acc[mt][1] = __builtin_amdgcn_mfma_f32_16x16x32_f16(af, bf[1], acc[mt][1], 0, 0, 0);
            }
            __syncthreads();
        }
        #pragma unroll
        for (int mt = 0; mt < 2; ++mt)
            #pragma unroll
            for (int nt = 0; nt < 2; ++nt)
                #pragma unroll
                for (int i = 0; i < 4; ++i)
                    T[(size_t)(m0 + wid*32 + mt*16 + lg*4 + i) * 64 + nt*16 + lr]
                        = (_Float16)acc[mt][nt][i];
    }
}

// ---------------- K3: Y = const + [z00|T] @ Och^T  (BM=64, BN=128; r11) ----------------
__global__ __launch_bounds__(256) void gemm_y_mfma(
    const _Float16* __restrict__ Z, const _Float16* __restrict__ T,
    const _Float16* __restrict__ Och, const float* __restrict__ cst,
    float* __restrict__ Y)
{
    __shared__ _Float16 As[64 * 104];
    __shared__ _Float16 Bs[128 * 104];
    const int t = threadIdx.x;
    const int n0 = blockIdx.x * 128, m0 = blockIdx.y * 64;
    {   // A: 64 rows x 96 = [z00 | T]; 4 threads/row, 24 halves each
        int row = t >> 2, seg = t & 3;
        const _Float16* zp = Z + (size_t)(m0 + row) * 192;
        const _Float16* tp = T + (size_t)(m0 + row) * 64;
        _Float16* dst = As + row * 104;
        if (seg == 0) {
            *(h8*)(dst)      = *(const h8*)(zp);
            *(h8*)(dst + 8)  = *(const h8*)(zp + 8);
            *(h8*)(dst + 16) = *(const h8*)(zp + 16);
        } else if (seg == 1) {
            *(h8*)(dst + 24) = *(const h8*)(zp + 24);
            *(h8*)(dst + 32) = *(const h8*)(tp);
            *(h8*)(dst + 40) = *(const h8*)(tp + 8);
        } else if (seg == 2) {
            *(h8*)(dst + 48) = *(const h8*)(tp + 16);
            *(h8*)(dst + 56) = *(const h8*)(tp + 24);
            *(h8*)(dst + 64) = *(const h8*)(tp + 32);
        } else {
            *(h8*)(dst + 72) = *(const h8*)(tp + 40);
            *(h8*)(dst + 80) = *(const h8*)(tp + 48);
            *(h8*)(dst + 88) = *(const h8*)(tp + 56);
        }
        // B: 128 rows x 96 Och
        int row2 = t >> 1, half = t & 1;
        const _Float16* src = Och + (size_t)(n0 + row2) * 96 + half * 48;
        _Float16* bdst = Bs + row2 * 104 + half * 48;
        #pragma unroll
        for (int q = 0; q < 6; ++q) *(h8*)(bdst + q * 8) = *(const h8*)(src + q * 8);
    }
    const int wid = t >> 6, lane = t & 63;
    const int wvr = wid >> 1, wvc = wid & 1;   // 2 m-waves x 2 n-waves
    const int lr = lane & 15, lg = lane >> 4;
    float bias[4];
    #pragma unroll
    for (int nt = 0; nt < 4; ++nt) bias[nt] = cst[n0 + wvc*64 + nt*16 + lr];
    __syncthreads();

    f4 acc[2][4];
    #pragma unroll
    for (int mt = 0; mt < 2; ++mt)
        #pragma unroll
        for (int nt = 0; nt < 4; ++nt) acc[mt][nt] = f4{0.f,0.f,0.f,0.f};

    #pragma unroll
    for (int ks = 0; ks < 3; ++ks) {
        h8 av[2], bv[4];
        #pragma unroll
        for (int mt = 0; mt < 2; ++mt)
            av[mt] = *(const h8*)&As[(wvr*32 + mt*16 + lr) * 104 + ks*32 + lg*8];
        #pragma unroll
        for (int nt = 0; nt < 4; ++nt)
            bv[nt] = *(const h8*)&Bs[(wvc*64 + nt*16 + lr) * 104 + ks*32 + lg*8];
        #pragma unroll
        for (int mt = 0; mt < 2; ++mt)
            #pragma unroll
            for (int nt = 0; nt < 4; ++nt)
                acc[mt][nt] = __builtin_amdgcn_mfma_f32_16x16x32_f16(av[mt], bv[nt], acc[mt][nt], 0, 0, 0);
    }
    #pragma unroll
    for (int mt = 0; mt < 2; ++mt)
        #pragma unroll
        for (int nt = 0; nt < 4; ++nt)
            #pragma unroll
            for (int i = 0; i < 4; ++i)
                Y[(size_t)(m0 + wvr*32 + mt*16 + lg*4 + i) * 1024 + n0 + wvc*64 + nt*16 + lr]
                    = acc[mt][nt][i] + bias[nt];
}

extern "C" void kernel_launch(void* const* d_in, const int* in_sizes, int n_in,
                              void* d_out, int out_size, void* d_ws, size_t ws_size,
                              hipStream_t stream) {
    const float* X   = (const float*)d_in[0];
    const float* cst = (const float*)d_in[1];
    const float* O0  = (const float*)d_in[2];
    const float* I0  = (const float*)d_in[3];
    const float* G0  = (const float*)d_in[4];
    const float* O1  = (const float*)d_in[5];
    const float* I1  = (const float*)d_in[6];
    const float* G1  = (const float*)d_in[7];
    const float* O2  = (const float*)d_in[8];
    const float* I2  = (const float*)d_in[9];
    const float* G2  = (const float*)d_in[10];
    unsigned char* ws = (unsigned char*)d_ws;
    _Float16* Zh  = (_Float16*)(ws + ZH_OFF);
    _Float16* Th  = (_Float16*)(ws + TH_OFF);
    _Float16* Oh  = (_Float16*)(ws + OCH_OFF);
    _Float16* G2h = (_Float16*)(ws + G2H_OFF);
    float* Y = (float*)d_out;

    prep_gemmx<<<1600, 256, 0, stream>>>(X, I0, I1, I2, O0, O1, O2, G0, G2, Oh, G2h, Zh);
    kron_fused<<<544, 256, 0, stream>>>(Zh, G2h, G1, Th);
    gemm_y_mfma<<<dim3(8, 64), 256, 0, stream>>>(Zh, Th, Oh, cst, Y);
}

// Round 18
// 36.517 us; speedup vs baseline: 1.2095x; 1.0762x over previous
//
#include <hip/hip_runtime.h>

// Fast Tucker-Taylor forward. Round 18: r17 + K1 X-GEMM wave-split-K
// (512 threads: group g computes K-half g*512..+511 in 8 steps; LDS reduce).
//   K1 prep_gemmx : 512-thr blocks; GEMM bx<192; G2 cvt 192..703; Och 704..895.
//   K2 kron_fused : t2 BM=128,BN=64, Q=2, 16 barriers, zu-prefetch (r17).
//   K3 gemm_y     : BM=64, BN=128 (r11).
//
// Z f16 cols: z00 0..31 | z10 32..63 | z11 64..95 | z20 96..127 | z21 128..159 | z22 160..191

typedef float f4 __attribute__((ext_vector_type(4)));
typedef _Float16 h8 __attribute__((ext_vector_type(8)));
typedef _Float16 h4 __attribute__((ext_vector_type(4)));
typedef unsigned int u32x4 __attribute__((ext_vector_type(4)));

// ws byte offsets
#define ZH_OFF  0u           // 4096*192 f16 = 1,572,864 B
#define TH_OFF  1572864u     // 4096*64 f16  =   524,288 B
#define OCH_OFF 2097152u     // 1024*96 f16  =   196,608 B
#define G2H_OFF 2293760u     // 1024*1024 f16 = 2,097,152 B (end 4,390,912)

__device__ __forceinline__ h8 splat8(unsigned int u) {
    _Float16 s = __builtin_bit_cast(_Float16, (unsigned short)(u & 0xffffu));
    return h8{ s, s, s, s, s, s, s, s };
}

// Integer-only broadcast-pair staging (r9 miscompile fix): 16 halves
// (2 x uint4) -> 16 u32 broadcast pairs.
__device__ __forceinline__ void stage_bcast16(const _Float16* zsrc, unsigned int* dst) {
    u32x4 u0 = *(const u32x4*)zsrc;
    u32x4 u1 = *(const u32x4*)(zsrc + 8);
    #pragma unroll
    for (int k = 0; k < 4; ++k) {
        dst[2*k]       = (u0[k] & 0xffffu) * 0x00010001u;
        dst[2*k + 1]   = (u0[k] >> 16)     * 0x00010001u;
        dst[8 + 2*k]   = (u1[k] & 0xffffu) * 0x00010001u;
        dst[8 + 2*k+1] = (u1[k] >> 16)     * 0x00010001u;
    }
}

// ---------------- K1: prep + X-GEMM (wave-split-K, 512 threads) ------------
__global__ __launch_bounds__(512) void prep_gemmx(
    const float* __restrict__ X,
    const float* __restrict__ I0, const float* __restrict__ I1, const float* __restrict__ I2,
    const float* __restrict__ O0, const float* __restrict__ O1, const float* __restrict__ O2,
    const float* __restrict__ G0, const float* __restrict__ G2,
    _Float16* __restrict__ Och, _Float16* __restrict__ G2h, _Float16* __restrict__ Z)
{
    const int bx = blockIdx.x;
    const int t = threadIdx.x;
    if (bx >= 192) {
        if (bx < 704) {            // G2 -> f16 (512 blocks x 512 thr x 4)
            int i = ((bx - 192) * 512 + t) * 4;
            f4 v = *(const f4*)(G2 + i);
            h4 o = { (_Float16)v[0], (_Float16)v[1], (_Float16)v[2], (_Float16)v[3] };
            *(h4*)(G2h + i) = o;
        } else {                   // Och (192 blocks x 512 thr)
            int idx = (bx - 704) * 512 + t;
            int o = idx / 96, j = idx - o * 96;
            float v;
            if (j < 32) {
                v = 0.f;
                #pragma unroll
                for (int q = 0; q < 32; ++q) v += O0[o*32 + q] * G0[q*32 + j];
            } else if (j < 64) v = O1[o*32 + (j - 32)];
            else               v = O2[o*32 + (j - 64)];
            Och[idx] = (_Float16)v;
        }
        return;
    }
    // ---- X-GEMM: wave-split-K. group g = K-half; 8 steps; LDS dbuf. ----
    __shared__ _Float16 As[2][2][64 * 64];     // [group][buf]
    __shared__ _Float16 Bs[2][2][64 * 64];
    const int g  = t >> 8;                     // 0 or 1
    const int tt = t & 255;
    const int work = (bx & 7) * 24 + (bx >> 3);       // XCD-chunked (192=8*24)
    const int m0 = (work / 3) * 64, n0 = (work % 3) * 64;
    const int wid = tt >> 6, lane = tt & 63;
    const int wr = wid >> 1, wc = wid & 1;
    const int lr = lane & 15, lg = lane >> 4;
    const int arow = tt >> 2, aq = tt & 3;

    const float* xbase = X + (size_t)(m0 + arow) * 1024 + g * 512 + aq * 16;
    const int wrow = n0 + arow;
    const float* wbase = (wrow < 32) ? I0 + (size_t)wrow * 1024
                       : (wrow < 96) ? I1 + (size_t)(wrow - 32) * 1024
                                     : I2 + (size_t)(wrow - 96) * 1024;
    wbase += g * 512 + aq * 16;
    const int sw0 = arow * 64 + (((aq * 2)     ^ (arow & 7)) << 3);
    const int sw1 = arow * 64 + (((aq * 2 + 1) ^ (arow & 7)) << 3);

    f4 xa[2][4], wa[2][4];
    #define LOADX(set, step) { \
        const float* xp = xbase + (step) * 64; \
        const float* wp = wbase + (step) * 64; \
        _Pragma("unroll") \
        for (int q = 0; q < 4; ++q) { xa[set][q] = *(const f4*)(xp + q*4); wa[set][q] = *(const f4*)(wp + q*4); } }
    #define STAGE(set, buf) { \
        h8 ha0, ha1, hb0, hb1; \
        _Pragma("unroll") \
        for (int j = 0; j < 4; ++j) { \
            ha0[j] = (_Float16)xa[set][0][j]; ha0[4+j] = (_Float16)xa[set][1][j]; \
            ha1[j] = (_Float16)xa[set][2][j]; ha1[4+j] = (_Float16)xa[set][3][j]; \
            hb0[j] = (_Float16)wa[set][0][j]; hb0[4+j] = (_Float16)wa[set][1][j]; \
            hb1[j] = (_Float16)wa[set][2][j]; hb1[4+j] = (_Float16)wa[set][3][j]; \
        } \
        *(h8*)&As[g][buf][sw0] = ha0; *(h8*)&As[g][buf][sw1] = ha1; \
        *(h8*)&Bs[g][buf][sw0] = hb0; *(h8*)&Bs[g][buf][sw1] = hb1; }

    LOADX(0, 0); LOADX(1, 1);
    STAGE(0, 0);
    LOADX(0, 2);

    f4 acc[2][2];
    #pragma unroll
    for (int mt = 0; mt < 2; ++mt)
        #pragma unroll
        for (int nt = 0; nt < 2; ++nt) acc[mt][nt] = f4{0.f,0.f,0.f,0.f};

    #pragma unroll
    for (int s = 0; s < 8; ++s) {
        const int cur = s & 1;
        __syncthreads();
        if (s < 7) STAGE((s + 1) & 1, cur ^ 1);
        if (s < 5) LOADX((s + 1) & 1, s + 3);
        #pragma unroll
        for (int ks = 0; ks < 2; ++ks) {
            h8 av[2], bv[2];
            #pragma unroll
            for (int mt = 0; mt < 2; ++mt) {
                int row = wr * 32 + mt * 16 + lr, gg = ks * 4 + lg;
                av[mt] = *(const h8*)&As[g][cur][row * 64 + ((gg ^ (row & 7)) << 3)];
            }
            #pragma unroll
            for (int nt = 0; nt < 2; ++nt) {
                int row = wc * 32 + nt * 16 + lr, gg = ks * 4 + lg;
                bv[nt] = *(const h8*)&Bs[g][cur][row * 64 + ((gg ^ (row & 7)) << 3)];
            }
            #pragma unroll
            for (int mt = 0; mt < 2; ++mt)
                #pragma unroll
                for (int nt = 0; nt < 2; ++nt)
                    acc[mt][nt] = __builtin_amdgcn_mfma_f32_16x16x32_f16(av[mt], bv[nt], acc[mt][nt], 0, 0, 0);
        }
    }
    #undef LOADX
    #undef STAGE
    // ---- reduce the two K-halves via LDS (16 KB, reuses dead tiles) ----
    __syncthreads();
    float* Red = (float*)&As[0][0][0];
    if (g == 1) {
        #pragma unroll
        for (int mt = 0; mt < 2; ++mt)
            #pragma unroll
            for (int nt = 0; nt < 2; ++nt)
                #pragma unroll
                for (int i = 0; i < 4; ++i)
                    Red[tt * 16 + mt * 8 + nt * 4 + i] = acc[mt][nt][i];
    }
    __syncthreads();
    if (g == 0) {
        #pragma unroll
        for (int mt = 0; mt < 2; ++mt)
            #pragma unroll
            for (int nt = 0; nt < 2; ++nt)
                #pragma unroll
                for (int i = 0; i < 4; ++i)
                    Z[(size_t)(m0 + wr*32 + mt*16 + lg*4 + i) * 192 + n0 + wc*32 + nt*16 + lr]
                        = (_Float16)(acc[mt][nt][i] + Red[tt * 16 + mt * 8 + nt * 4 + i]);
    }
}

// ---------------- K2: fused kron t2 + t1 (r17 verbatim) ----------------
__global__ __launch_bounds__(256) void kron_fused(
    const _Float16* __restrict__ Z, const _Float16* __restrict__ G2h,
    const float* __restrict__ G1, _Float16* __restrict__ T)
{
    __shared__ __align__(16) unsigned char smem[37376];
    unsigned int* Zs1 = (unsigned int*)smem;               // [128][33]
    _Float16* Bs = (_Float16*)(smem + 16896);              // t2: [2][2][64][40]; t1: [2][32][40]
    const int bx = blockIdx.x;
    const int t = threadIdx.x;
    const int wid = t >> 6, lane = t & 63;
    const int lr = lane & 15, lg = lane >> 4;
    const bool is_t2 = bx < 512;
    const int m0 = is_t2 ? (bx >> 4) * 128 : (bx - 512) * 128;
    const int zcol = is_t2 ? 128 : 64;                     // z21 vs z11

    {   // outer z factor -> broadcast u32 pairs (integer-only)
        int row = t >> 1, c0 = (t & 1) * 16;
        stage_bcast16(Z + (size_t)(m0 + row) * 192 + zcol + c0, Zs1 + row * 33 + c0);
    }

    if (is_t2) {
        const int n0 = (bx & 15) * 64;
        const int wm0 = (wid >> 1) * 64, wn0 = (wid & 1) * 32;
        h8 a0v[4];
        #pragma unroll
        for (int mt = 0; mt < 4; ++mt)
            a0v[mt] = *(const h8*)(Z + (size_t)(m0 + wm0 + mt*16 + lr) * 192 + 96 + lg * 8);

        f4 acc[4][2];
        #pragma unroll
        for (int mt = 0; mt < 4; ++mt)
            #pragma unroll
            for (int nt = 0; nt < 2; ++nt) acc[mt][nt] = f4{0.f, 0.f, 0.f, 0.f};

        const int brow = t >> 2, bg = t & 3;
        const f4* gsrc = (const f4*)(G2h + (size_t)(n0 + brow) * 1024 + bg * 8);
        f4 brA[2], brB[2];
        brA[0] = gsrc[0];  brB[0] = gsrc[4];     // interval 0
        {
            *(f4*)&Bs[0 * 5120 + 0 * 2560 + brow * 40 + bg * 8] = brA[0];
            *(f4*)&Bs[0 * 5120 + 1 * 2560 + brow * 40 + bg * 8] = brB[0];
        }
        brA[1] = gsrc[8];  brB[1] = gsrc[12];    // interval 1
        brA[0] = gsrc[16]; brB[0] = gsrc[20];    // interval 2

        unsigned int zu[2][2][4];                // [set][q][mt] Zs1 prefetch
        #pragma unroll
        for (int i = 0; i < 16; ++i) {
            const int cur = i & 1;
            __syncthreads();
            if (i == 0) {
                #pragma unroll
                for (int q = 0; q < 2; ++q)
                    #pragma unroll
                    for (int mt = 0; mt < 4; ++mt)
                        zu[0][q][mt] = Zs1[(wm0 + mt*16 + lr) * 33 + q];
            }
            if (i < 15) {
                const int set = (i + 1) & 1;
                *(f4*)&Bs[(cur ^ 1) * 5120 + 0 * 2560 + brow * 40 + bg * 8] = brA[set];
                *(f4*)&Bs[(cur ^ 1) * 5120 + 1 * 2560 + brow * 40 + bg * 8] = brB[set];
                #pragma unroll
                for (int q = 0; q < 2; ++q)
                    #pragma unroll
                    for (int mt = 0; mt < 4; ++mt)
                        zu[set][q][mt] = Zs1[(wm0 + mt*16 + lr) * 33 + 2*(i+1) + q];
            }
            if (i < 13) {
                const int set = (i + 1) & 1;
                brA[set] = gsrc[(i + 3) * 8];
                brB[set] = gsrc[(i + 3) * 8 + 4];
            }
            #pragma unroll
            for (int q = 0; q < 2; ++q) {
                h8 bf0 = *(const h8*)&Bs[cur * 5120 + q * 2560 + (wn0 + lr) * 40 + lg * 8];
                h8 bf1 = *(const h8*)&Bs[cur * 5120 + q * 2560 + (wn0 + 16 + lr) * 40 + lg * 8];
                #pragma unroll
                for (int mt = 0; mt < 4; ++mt) {
                    h8 z1b = splat8(zu[cur][q][mt]);
                    h8 af = z1b * a0v[mt];
                    acc[mt][0] = __builtin_amdgcn_mfma_f32_16x16x32_f16(af, bf0, acc[mt][0], 0, 0, 0);
                    acc[mt][1] = __builtin_amdgcn_mfma_f32_16x16x32_f16(af, bf1, acc[mt][1], 0, 0, 0);
                }
            }
        }

        __syncthreads();
        float* Ms = (float*)smem;                          // [128][66]
        #pragma unroll
        for (int mt = 0; mt < 4; ++mt)
            #pragma unroll
            for (int nt = 0; nt < 2; ++nt)
                #pragma unroll
                for (int i = 0; i < 4; ++i)
                    Ms[(wm0 + mt*16 + lg*4 + i) * 66 + wn0 + nt*16 + lr] = acc[mt][nt][i];
        __syncthreads();
        {
            int row = t >> 1, rl = t & 1;
            const _Float16* z2p = Z + (size_t)(m0 + row) * 192 + 160;
            const float* mrow = Ms + row * 66 + rl * 32;
            float sum = 0.f;
            #pragma unroll
            for (int r2 = 0; r2 < 32; ++r2) sum += mrow[r2] * (float)z2p[r2];
            T[(size_t)(m0 + row) * 64 + 32 + (bx & 15) * 2 + rl] = (_Float16)sum;
        }
    } else {
        // ---- t1: kron(z11,z10) @ G1^T (r11 verbatim) ----
        h8 a0v[2];
        #pragma unroll
        for (int mt = 0; mt < 2; ++mt)
            a0v[mt] = *(const h8*)(Z + (size_t)(m0 + wid*32 + mt*16 + lr) * 192 + 32 + lg * 8);

        const int brow = t >> 3, bq = (t & 7) * 4;
        const float* g1src = G1 + (size_t)brow * 1024 + bq;
        f4 bw = *(const f4*)g1src;
        {
            h4 bh = { (_Float16)bw[0], (_Float16)bw[1], (_Float16)bw[2], (_Float16)bw[3] };
            *(h4*)&Bs[brow * 40 + bq] = bh;
        }
        bw = *(const f4*)(g1src + 32);

        f4 acc[2][2];
        #pragma unroll
        for (int mt = 0; mt < 2; ++mt)
            #pragma unroll
            for (int nt = 0; nt < 2; ++nt) acc[mt][nt] = f4{0.f,0.f,0.f,0.f};
        __syncthreads();

        for (int s = 0; s < 32; ++s) {
            const int cur = s & 1;
            if (s < 31) {
                h4 bh = { (_Float16)bw[0], (_Float16)bw[1], (_Float16)bw[2], (_Float16)bw[3] };
                *(h4*)&Bs[(cur ^ 1) * 1280 + brow * 40 + bq] = bh;
            }
            if (s < 30) bw = *(const f4*)(g1src + (s + 2) * 32);
            h8 bf[2];
            #pragma unroll
            for (int nt = 0; nt < 2; ++nt)
                bf[nt] = *(const h8*)&Bs[cur * 1280 + (nt*16 + lr) * 40 + lg * 8];
            #pragma unroll
            for (int mt = 0; mt < 2; ++mt) {
                h8 z1b = splat8(Zs1[(wid*32 + mt*16 + lr) * 33 + s]);
                h8 af = z1b * a0v[mt];
                acc[mt][0] = __builtin_amdgcn_mfma_f32_16x16x32_f16(af, bf[0], acc[mt][0], 0, 0, 0);
                acc[mt][1] = __builtin_amdgcn_mfma_f32_16x16x32_f16(af, bf[1], acc[mt][1], 0, 0, 0);
            }
            __syncthreads();
        }
        #pragma unroll
        for (int mt = 0; mt < 2; ++mt)
            #pragma unroll
            for (int nt = 0; nt < 2; ++nt)
                #pragma unroll
                for (int i = 0; i < 4; ++i)
                    T[(size_t)(m0 + wid*32 + mt*16 + lg*4 + i) * 64 + nt*16 + lr]
                        = (_Float16)acc[mt][nt][i];
    }
}

// ---------------- K3: Y = const + [z00|T] @ Och^T  (BM=64, BN=128; r11) ----------------
__global__ __launch_bounds__(256) void gemm_y_mfma(
    const _Float16* __restrict__ Z, const _Float16* __restrict__ T,
    const _Float16* __restrict__ Och, const float* __restrict__ cst,
    float* __restrict__ Y)
{
    __shared__ _Float16 As[64 * 104];
    __shared__ _Float16 Bs[128 * 104];
    const int t = threadIdx.x;
    const int n0 = blockIdx.x * 128, m0 = blockIdx.y * 64;
    {   // A: 64 rows x 96 = [z00 | T]; 4 threads/row, 24 halves each
        int row = t >> 2, seg = t & 3;
        const _Float16* zp = Z + (size_t)(m0 + row) * 192;
        const _Float16* tp = T + (size_t)(m0 + row) * 64;
        _Float16* dst = As + row * 104;
        if (seg == 0) {
            *(h8*)(dst)      = *(const h8*)(zp);
            *(h8*)(dst + 8)  = *(const h8*)(zp + 8);
            *(h8*)(dst + 16) = *(const h8*)(zp + 16);
        } else if (seg == 1) {
            *(h8*)(dst + 24) = *(const h8*)(zp + 24);
            *(h8*)(dst + 32) = *(const h8*)(tp);
            *(h8*)(dst + 40) = *(const h8*)(tp + 8);
        } else if (seg == 2) {
            *(h8*)(dst + 48) = *(const h8*)(tp + 16);
            *(h8*)(dst + 56) = *(const h8*)(tp + 24);
            *(h8*)(dst + 64) = *(const h8*)(tp + 32);
        } else {
            *(h8*)(dst + 72) = *(const h8*)(tp + 40);
            *(h8*)(dst + 80) = *(const h8*)(tp + 48);
            *(h8*)(dst + 88) = *(const h8*)(tp + 56);
        }
        // B: 128 rows x 96 Och
        int row2 = t >> 1, half = t & 1;
        const _Float16* src = Och + (size_t)(n0 + row2) * 96 + half * 48;
        _Float16* bdst = Bs + row2 * 104 + half * 48;
        #pragma unroll
        for (int q = 0; q < 6; ++q) *(h8*)(bdst + q * 8) = *(const h8*)(src + q * 8);
    }
    const int wid = t >> 6, lane = t & 63;
    const int wvr = wid >> 1, wvc = wid & 1;   // 2 m-waves x 2 n-waves
    const int lr = lane & 15, lg = lane >> 4;
    float bias[4];
    #pragma unroll
    for (int nt = 0; nt < 4; ++nt) bias[nt] = cst[n0 + wvc*64 + nt*16 + lr];
    __syncthreads();

    f4 acc[2][4];
    #pragma unroll
    for (int mt = 0; mt < 2; ++mt)
        #pragma unroll
        for (int nt = 0; nt < 4; ++nt) acc[mt][nt] = f4{0.f,0.f,0.f,0.f};

    #pragma unroll
    for (int ks = 0; ks < 3; ++ks) {
        h8 av[2], bv[4];
        #pragma unroll
        for (int mt = 0; mt < 2; ++mt)
            av[mt] = *(const h8*)&As[(wvr*32 + mt*16 + lr) * 104 + ks*32 + lg*8];
        #pragma unroll
        for (int nt = 0; nt < 4; ++nt)
            bv[nt] = *(const h8*)&Bs[(wvc*64 + nt*16 + lr) * 104 + ks*32 + lg*8];
        #pragma unroll
        for (int mt = 0; mt < 2; ++mt)
            #pragma unroll
            for (int nt = 0; nt < 4; ++nt)
                acc[mt][nt] = __builtin_amdgcn_mfma_f32_16x16x32_f16(av[mt], bv[nt], acc[mt][nt], 0, 0, 0);
    }
    #pragma unroll
    for (int mt = 0; mt < 2; ++mt)
        #pragma unroll
        for (int nt = 0; nt < 4; ++nt)
            #pragma unroll
            for (int i = 0; i < 4; ++i)
                Y[(size_t)(m0 + wvr*32 + mt*16 + lg*4 + i) * 1024 + n0 + wvc*64 + nt*16 + lr]
                    = acc[mt][nt][i] + bias[nt];
}

extern "C" void kernel_launch(void* const* d_in, const int* in_sizes, int n_in,
                              void* d_out, int out_size, void* d_ws, size_t ws_size,
                              hipStream_t stream) {
    const float* X   = (const float*)d_in[0];
    const float* cst = (const float*)d_in[1];
    const float* O0  = (const float*)d_in[2];
    const float* I0  = (const float*)d_in[3];
    const float* G0  = (const float*)d_in[4];
    const float* O1  = (const float*)d_in[5];
    const float* I1  = (const float*)d_in[6];
    const float* G1  = (const float*)d_in[7];
    const float* O2  = (const float*)d_in[8];
    const float* I2  = (const float*)d_in[9];
    const float* G2  = (const float*)d_in[10];
    unsigned char* ws = (unsigned char*)d_ws;
    _Float16* Zh  = (_Float16*)(ws + ZH_OFF);
    _Float16* Th  = (_Float16*)(ws + TH_OFF);
    _Float16* Oh  = (_Float16*)(ws + OCH_OFF);
    _Float16* G2h = (_Float16*)(ws + G2H_OFF);
    float* Y = (float*)d_out;

    prep_gemmx<<<896, 512, 0, stream>>>(X, I0, I1, I2, O0, O1, O2, G0, G2, Oh, G2h, Zh);
    kron_fused<<<544, 256, 0, stream>>>(Zh, G2h, G1, Th);
    gemm_y_mfma<<<dim3(8, 64), 256, 0, stream>>>(Zh, Th, Oh, cst, Y);
}